// Round 16
// baseline (235.974 us; speedup 1.0000x reference)
//
#include <hip/hip_runtime.h>
#include <math.h>

#define E 768
#define NTOK 4096  /* BATCH*S */

typedef __attribute__((ext_vector_type(8))) __bf16 bf16x8;
typedef __attribute__((ext_vector_type(4))) float f32x4;
typedef unsigned int u32;
typedef unsigned short u16;
typedef __attribute__((ext_vector_type(4))) u32 u32x4;

#define BFN ((size_t)NTOK * E)
#define WFN ((size_t)E * E)
#define QSC 1.4901161193847656e-08f   /* 2^-26 */
#define C2E 0.18033688011112042f      /* 0.125 * log2(e) */

__device__ __forceinline__ float sp_f(float x) {
    return fmaxf(x, 0.f) + log1pf(__expf(-fabsf(x)));
}
__device__ __forceinline__ u16 f2bf(float f) {
    u32 u = __float_as_uint(f);
    u += 0x7fffu + ((u >> 16) & 1u);
    return (u16)(u >> 16);
}
__device__ __forceinline__ u32 pk2(float a, float b) {
    return (u32)f2bf(a) | ((u32)f2bf(b) << 16);
}
__device__ __forceinline__ u32 cvtpk(float a, float b) {
    u32 r; asm("v_cvt_pk_bf16_f32 %0, %1, %2" : "=v"(r) : "v"(a), "v"(b)); return r;
}
__device__ __forceinline__ float ex2(float x) {
    float r; asm("v_exp_f32 %0, %1" : "=v"(r) : "v"(x)); return r;
}
__device__ __forceinline__ float lg2(float x) {
    float r; asm("v_log_f32 %0, %1" : "=v"(r) : "v"(x)); return r;
}
__device__ __forceinline__ float bfl(u32 u) { return __uint_as_float(u << 16); }
__device__ __forceinline__ float bfh(u32 u) { return __uint_as_float(u & 0xffff0000u); }

#define GLL16(gp, lp) __builtin_amdgcn_global_load_lds( \
    (const __attribute__((address_space(1))) u32*)(gp), \
    (__attribute__((address_space(3))) u32*)(lp), 16, 0, 0)

#define SBAR() do { __builtin_amdgcn_sched_barrier(0); \
                    __builtin_amdgcn_s_barrier(); \
                    __builtin_amdgcn_sched_barrier(0); } while (0)
#define VMCNT(N) do { asm volatile("s_waitcnt vmcnt(" #N ")" ::: "memory"); \
                      __builtin_amdgcn_sched_barrier(0); } while (0)

// ----------------------------------------------------------- prep (fused) --
// blocks [0,2048): fp32->bf16 conv + input row stats (2 rows/block)
// blocks [2048,4352): weight transpose+square, FUSED KL partial (each W
//   element read exactly once here); rem==0 block per matrix adds sigma terms
// block 4352: softplus(w_sigma) table
__global__ __launch_bounds__(256) void prep_all(
    const float* __restrict__ mu_in, const float* __restrict__ sg_in,
    const float* __restrict__ wq, const float* __restrict__ wk,
    const float* __restrict__ wvp, const float* __restrict__ wo,
    const float* __restrict__ wqs, const float* __restrict__ wks,
    const float* __restrict__ wvs, const float* __restrict__ wos,
    u16* __restrict__ Xmu, u16* __restrict__ Xsg,
    float* __restrict__ rmu2, float* __restrict__ rsg,
    u16* __restrict__ WtAll, u16* __restrict__ W2tAll,
    float* __restrict__ spws, float* __restrict__ kl_out)
{
    __shared__ float T[32][33];
    __shared__ float r1[4], r2[4];
    const int b = blockIdx.x, tid = threadIdx.x;

    if (b < 2048) {
        const int half = tid >> 7;
        const int n = b * 2 + half;
        const int t2 = tid & 127;
        float s1 = 0.f, s2 = 0.f;
        if (t2 < 96) {
            size_t o = (size_t)n * E + t2 * 8;
            float4 a0 = *(const float4*)(mu_in + o), a1 = *(const float4*)(mu_in + o + 4);
            float4 b0 = *(const float4*)(sg_in + o), b1 = *(const float4*)(sg_in + o + 4);
            *(uint4*)(Xmu + o) = make_uint4(pk2(a0.x, a0.y), pk2(a0.z, a0.w), pk2(a1.x, a1.y), pk2(a1.z, a1.w));
            *(uint4*)(Xsg + o) = make_uint4(pk2(b0.x, b0.y), pk2(b0.z, b0.w), pk2(b1.x, b1.y), pk2(b1.z, b1.w));
            s1 = a0.x*a0.x + a0.y*a0.y + a0.z*a0.z + a0.w*a0.w + a1.x*a1.x + a1.y*a1.y + a1.z*a1.z + a1.w*a1.w;
            s2 = b0.x + b0.y + b0.z + b0.w + b1.x + b1.y + b1.z + b1.w;
        }
        for (int off = 32; off; off >>= 1) {
            s1 += __shfl_xor(s1, off);
            s2 += __shfl_xor(s2, off);
        }
        if ((tid & 63) == 0) { r1[tid >> 6] = s1; r2[tid >> 6] = s2; }
        __syncthreads();
        if (t2 == 0) {
            rmu2[n] = r1[half * 2] + r1[half * 2 + 1];
            rsg[n]  = r2[half * 2] + r2[half * 2 + 1];
        }
    } else if (b < 4352) {
        const int b2 = b - 2048;
        const int z = b2 / 576, rem = b2 - z * 576;
        const float* W = (z == 0) ? wq : (z == 1) ? wk : (z == 2) ? wvp : wo;
        u16* Wt  = WtAll  + (size_t)z * WFN;
        u16* W2t = W2tAll + (size_t)z * WFN;
        const int j0 = (rem % 24) * 32, k0 = (rem / 24) * 32;
        const int r = tid >> 3, c = (tid & 7) * 4;
        float4 v = *(const float4*)(W + (size_t)(k0 + r) * E + j0 + c);
        // KL partial: every W element passes through here exactly once
        const float cw = 100.f / ((float)E * (float)E);
        float ka = (v.x * v.x + v.y * v.y + v.z * v.z + v.w * v.w) * cw;
        if (rem == 0) {
            const float* sv = (z == 0) ? wqs : (z == 1) ? wks : (z == 2) ? wvs : wos;
            for (int i = tid; i < E; i += 256) {
                float x = sv[i];
                ka += (-x + sp_f(x) * 100.f) * (1.f / (float)E);
            }
            if (b == 2048 && tid == 0) ka += 4.f * (logf(0.01f) - 1.f);
        }
        T[r][c] = v.x; T[r][c + 1] = v.y; T[r][c + 2] = v.z; T[r][c + 3] = v.w;
        __syncthreads();
        const int j = tid >> 3, kc = (tid & 7) * 4;
        float w0 = T[kc][j], w1 = T[kc + 1][j], w2 = T[kc + 2][j], w3 = T[kc + 3][j];
        size_t o = (size_t)(j0 + j) * E + k0 + kc;
        *(uint2*)(Wt + o) = make_uint2(pk2(w0, w1), pk2(w2, w3));
        const float s = 1.f / 768.f;
        *(uint2*)(W2t + o) = make_uint2(pk2(w0 * w0 * s, w1 * w1 * s), pk2(w2 * w2 * s, w3 * w3 * s));
        // KL reduce + one atomic per block
        for (int off = 32; off; off >>= 1) ka += __shfl_xor(ka, off);
        if ((tid & 63) == 0) r1[tid >> 6] = ka;
        __syncthreads();
        if (tid == 0) atomicAdd(kl_out, 0.5f * (r1[0] + r1[1] + r1[2] + r1[3]));
    } else {
        for (int i = tid; i < 4 * E; i += 256) {
            const float* src;
            int j;
            if (i < E)            { src = wqs; j = i; }
            else if (i < 2 * E)   { src = wks; j = i - E; }
            else if (i < 3 * E)   { src = wvs; j = i - 2 * E; }
            else                  { src = wos; j = i - 3 * E; }
            spws[i] = sp_f(src[j]);
        }
    }
}

// --------------------------------- QKV linear (round-9/15 proven) ---------
// 128x64 tile, BK=32, NBUF=2, 48KB LDS, 3 blocks/CU, XCD m-fastest.
__global__ __launch_bounds__(256, 3) void linear_qkv(
    const u16* __restrict__ Am, const u16* __restrict__ As,
    const u16* __restrict__ Wt, const u16* __restrict__ W2t,
    const float* __restrict__ spws, const float* __restrict__ rmu2, const float* __restrict__ rsg,
    u16* __restrict__ QKVB)
{
    __shared__ __align__(16) u16 L[24576];

    const int wgid = blockIdx.x;
    const int xcd = wgid & 7, local = wgid >> 3;
    const int m_blk = xcd * 4 + (local & 3);
    const int n_blk = local >> 2;
    const int m0 = m_blk * 128, col0 = n_blk * 64;
    const int tid = threadIdx.x, wv = tid >> 6, lane = tid & 63;
    const int g = lane >> 4, q15 = lane & 15;

    const u16* sp_[6];
    {
        const int rA = tid >> 2, cA = tid & 3;
        const int rB = 64 + rA;
        const int csA = (cA ^ ((rA >> 1) & 3)) << 3;
        const int csB = (cA ^ ((rB >> 1) & 3)) << 3;
        sp_[0] = Am  + (size_t)(m0 + rA) * E + csA;
        sp_[1] = Am  + (size_t)(m0 + rB) * E + csB;
        sp_[2] = As  + (size_t)(m0 + rA) * E + csA;
        sp_[3] = As  + (size_t)(m0 + rB) * E + csB;
        sp_[4] = Wt  + (size_t)(col0 + rA) * E + csA;
        sp_[5] = W2t + (size_t)(col0 + rA) * E + csA;
    }

    f32x4 acc1[2][4], acc2[2][4];
#pragma unroll
    for (int mt = 0; mt < 2; ++mt)
#pragma unroll
        for (int nt = 0; nt < 4; ++nt) {
            acc1[mt][nt] = (f32x4){0.f, 0.f, 0.f, 0.f};
            acc2[mt][nt] = (f32x4){0.f, 0.f, 0.f, 0.f};
        }

#pragma unroll
    for (int j = 0; j < 6; ++j)
        GLL16(sp_[j], &L[j * 2048 + tid * 8]);

    for (int t = 0; t < 24; ++t) {
        SBAR();
        const int tn = (t < 23) ? t + 1 : 23;
        const int nb = ((t & 1) ^ 1) * 12288;
#pragma unroll
        for (int j = 0; j < 6; ++j)
            GLL16(sp_[j] + tn * 32, &L[nb + j * 2048 + tid * 8]);
        VMCNT(6);
        SBAR();
        const int cb = (t & 1) * 12288;
        bf16x8 am[2], asg[2];
#pragma unroll
        for (int mt = 0; mt < 2; ++mt) {
            int r = wv * 32 + mt * 16 + q15;
            int c = (g ^ ((r >> 1) & 3)) << 3;
            am[mt]  = *(const bf16x8*)&L[cb + r * 32 + c];
            asg[mt] = *(const bf16x8*)&L[cb + 4096 + r * 32 + c];
        }
        __builtin_amdgcn_s_setprio(1);
#pragma unroll
        for (int nt = 0; nt < 4; ++nt) {
            int rb = nt * 16 + q15;
            int c = (g ^ ((rb >> 1) & 3)) << 3;
            bf16x8 bw = *(const bf16x8*)&L[cb + 8192 + rb * 32 + c];
            bf16x8 b2 = *(const bf16x8*)&L[cb + 10240 + rb * 32 + c];
            acc1[0][nt] = __builtin_amdgcn_mfma_f32_16x16x32_bf16(am[0], bw, acc1[0][nt], 0, 0, 0);
            acc1[1][nt] = __builtin_amdgcn_mfma_f32_16x16x32_bf16(am[1], bw, acc1[1][nt], 0, 0, 0);
            acc2[0][nt] = __builtin_amdgcn_mfma_f32_16x16x32_bf16(asg[0], b2, acc2[0][nt], 0, 0, 0);
            acc2[1][nt] = __builtin_amdgcn_mfma_f32_16x16x32_bf16(asg[1], b2, acc2[1][nt], 0, 0, 0);
        }
        __builtin_amdgcn_s_setprio(0);
    }
    __syncthreads();

    const float inv2 = 1.f / (768.f * 768.f), invd = 1.f / 768.f;
    float rr[2][4];
#pragma unroll
    for (int mt = 0; mt < 2; ++mt)
#pragma unroll
        for (int r = 0; r < 4; ++r) {
            int row = m0 + wv * 32 + mt * 16 + g * 4 + r;
            rr[mt][r] = rmu2[row] * inv2 + rsg[row] * invd;
        }

    const int proj = n_blk / 12, h = n_blk % 12;
    float sgv[2][4][4];
#pragma unroll
    for (int mt = 0; mt < 2; ++mt)
#pragma unroll
        for (int nt = 0; nt < 4; ++nt)
#pragma unroll
            for (int r = 0; r < 4; ++r) {
                int col = col0 + nt * 16 + q15;
                sgv[mt][nt][r] = sp_f(acc2[mt][nt][r] + rr[mt][r] * spws[col]);
            }
    const int bb = m0 >> 10;
    if (proj < 2) {
        const int s0 = (m0 & 1023);
        const int sl = tid >> 1, hh = tid & 1;
        size_t gbase = ((size_t)(bb * 12 + h) << 16) + ((size_t)(s0 + sl) << 6) + hh * 32;
#pragma unroll
        for (int a = 0; a < 3; ++a) {
            __syncthreads();
#pragma unroll
            for (int mt = 0; mt < 2; ++mt)
#pragma unroll
                for (int nt = 0; nt < 4; ++nt)
#pragma unroll
                    for (int r = 0; r < 4; ++r) {
                        float mu = acc1[mt][nt][r], sg = sgv[mt][nt][r];
                        float v = (a == 0) ? mu : (a == 1) ? sg :
                                  (proj == 0 ? (mu * mu + sg) * QSC : mu * mu * QSC);
                        L[(wv * 32 + mt * 16 + g * 4 + r) * 72 + nt * 16 + q15] = f2bf(v);
                    }
            __syncthreads();
            u16* dst = QKVB + (size_t)(proj * 3 + a) * BFN;
#pragma unroll
            for (int j = 0; j < 4; ++j)
                *(uint4*)(dst + gbase + j * 8) = *(const uint4*)&L[sl * 72 + hh * 32 + j * 8];
        }
    } else {
        const int s0 = m0 & 1023;
#pragma unroll
        for (int a = 0; a < 3; ++a) {
            __syncthreads();
#pragma unroll
            for (int mt = 0; mt < 2; ++mt)
#pragma unroll
                for (int nt = 0; nt < 4; ++nt)
#pragma unroll
                    for (int r = 0; r < 4; ++r) {
                        float mu = acc1[mt][nt][r], sg = sgv[mt][nt][r];
                        float v = (a == 0) ? mu : (a == 1) ? sg * 0.0009765625f : mu * mu + sg;
                        L[(nt * 16 + q15) * 136 + wv * 32 + g * 8 + mt * 4 + r] = f2bf(v);
                    }
            __syncthreads();
            const int d = tid >> 2, sc = (tid & 3) * 32;
            u16* dst = QKVB + (size_t)(6 + a) * BFN;
            size_t ga = ((size_t)((bb * 12 + h) * 64 + d) << 10) + s0 + sc;
            *(uint4*)(dst + ga)      = *(const uint4*)&L[d * 136 + sc];
            *(uint4*)(dst + ga + 8)  = *(const uint4*)&L[d * 136 + sc + 8];
            *(uint4*)(dst + ga + 16) = *(const uint4*)&L[d * 136 + sc + 16];
            *(uint4*)(dst + ga + 24) = *(const uint4*)&L[d * 136 + sc + 24];
        }
    }
}

// ------------------------- O-proj: 64x64 tile, grid 768 = 3 blocks/CU ------
__global__ __launch_bounds__(256, 3) void linear_oproj64(
    const u16* __restrict__ Am, const u16* __restrict__ As,
    const u16* __restrict__ Wt, const u16* __restrict__ W2t,
    const float* __restrict__ spws, const float* __restrict__ rmu2, const float* __restrict__ rsg,
    float* __restrict__ mu_out, float* __restrict__ sg_out)
{
    __shared__ __align__(16) u16 L[16384];   // 32KB = 2 x 8192

    const int wgid = blockIdx.x;             // 768 = 8 xcd x (8 m x 12 n)
    const int xcd = wgid & 7, local = wgid >> 3;
    const int m_blk = xcd * 8 + (local & 7); // m fastest within chunk
    const int n_blk = local >> 3;            // [0,12)
    const int m0 = m_blk * 64, col0 = n_blk * 64;
    const int tid = threadIdx.x, wv = tid >> 6, lane = tid & 63;
    const int g = lane >> 4, q15 = lane & 15;

    const u16* sp_[4];
    {
        const int r = tid >> 2, c = tid & 3;
        const int cs = (c ^ ((r >> 1) & 3)) << 3;
        sp_[0] = Am  + (size_t)(m0 + r) * E + cs;
        sp_[1] = As  + (size_t)(m0 + r) * E + cs;
        sp_[2] = Wt  + (size_t)(col0 + r) * E + cs;
        sp_[3] = W2t + (size_t)(col0 + r) * E + cs;
    }

    f32x4 acc1[4], acc2[4];
#pragma unroll
    for (int nt = 0; nt < 4; ++nt) {
        acc1[nt] = (f32x4){0.f, 0.f, 0.f, 0.f};
        acc2[nt] = (f32x4){0.f, 0.f, 0.f, 0.f};
    }

#pragma unroll
    for (int j = 0; j < 4; ++j)
        GLL16(sp_[j], &L[j * 2048 + tid * 8]);

    for (int t = 0; t < 24; ++t) {
        SBAR();
        const int tn = (t < 23) ? t + 1 : 23;
        const int nb = ((t & 1) ^ 1) * 8192;
#pragma unroll
        for (int j = 0; j < 4; ++j)
            GLL16(sp_[j] + tn * 32, &L[nb + j * 2048 + tid * 8]);
        VMCNT(4);
        SBAR();
        const int cb = (t & 1) * 8192;
        int rA = wv * 16 + q15;
        int cA = (g ^ ((rA >> 1) & 3)) << 3;
        bf16x8 am  = *(const bf16x8*)&L[cb + rA * 32 + cA];
        bf16x8 asg = *(const bf16x8*)&L[cb + 2048 + rA * 32 + cA];
        __builtin_amdgcn_s_setprio(1);
#pragma unroll
        for (int nt = 0; nt < 4; ++nt) {
            int rb = nt * 16 + q15;
            int c = (g ^ ((rb >> 1) & 3)) << 3;
            bf16x8 bw = *(const bf16x8*)&L[cb + 4096 + rb * 32 + c];
            bf16x8 b2 = *(const bf16x8*)&L[cb + 6144 + rb * 32 + c];
            acc1[nt] = __builtin_amdgcn_mfma_f32_16x16x32_bf16(am,  bw, acc1[nt], 0, 0, 0);
            acc2[nt] = __builtin_amdgcn_mfma_f32_16x16x32_bf16(asg, b2, acc2[nt], 0, 0, 0);
        }
        __builtin_amdgcn_s_setprio(0);
    }

    const float inv2 = 1.f / (768.f * 768.f), invd = 1.f / 768.f;
#pragma unroll
    for (int r = 0; r < 4; ++r) {
        int row = m0 + wv * 16 + g * 4 + r;
        float rr = rmu2[row] * inv2 + rsg[row] * invd;
#pragma unroll
        for (int nt = 0; nt < 4; ++nt) {
            int col = col0 + nt * 16 + q15;
            float mu = acc1[nt][r];
            float sg = sp_f(sp_f(acc2[nt][r] + rr * spws[col]));
            mu_out[(size_t)row * E + col] = mu;
            sg_out[(size_t)row * E + col] = sg;
        }
    }
}

// ------------------------------------------------------------- attention ---
// v9 (round-15 proven): pass 1 = 128-k tiles (8 rounds); pass 2 = K+V dbuf;
// epilogue fuses row stats via 16-lane shfl reduce + atomicAdd.
#define KB0 0
#define KB1 6144
#define VB0 12288
#define VB1 18432
__global__ __launch_bounds__(256, 3) void vdp_attn9(
    const u16* __restrict__ Kmu, const u16* __restrict__ Ksg, const u16* __restrict__ Asq,
    const u16* __restrict__ Qmu, const u16* __restrict__ Q1v, const u16* __restrict__ Q2v,
    const u16* __restrict__ Vmu, const u16* __restrict__ Vsg, const u16* __restrict__ Vw2,
    u16* __restrict__ om, u16* __restrict__ osg,
    float* __restrict__ armu2, float* __restrict__ arsg)
{
    __shared__ __align__(16) u16 L[24576];   // 48KB

    const int wgid = blockIdx.x;                  // 768 = 48bh x 16qt
    const int seq = (wgid & 7) * 96 + (wgid >> 3);
    const int bh = seq >> 4, qt = seq & 15;
    const int tid = threadIdx.x, wv = tid >> 6, lane = tid & 63;
    const int g = lane >> 4, q15 = lane & 15;
    const size_t hb = (size_t)bh << 16;

    const size_t qoff = hb + (size_t)((qt * 64 + wv * 16 + q15) << 6) + g * 8;
    bf16x8 bq0 = *(const bf16x8*)(Qmu + qoff), bq1 = *(const bf16x8*)(Qmu + qoff + 32);
    bf16x8 b10 = *(const bf16x8*)(Q1v + qoff), b11 = *(const bf16x8*)(Q1v + qoff + 32);
    bf16x8 b20 = *(const bf16x8*)(Q2v + qoff), b21 = *(const bf16x8*)(Q2v + qoff + 32);

    const int sr = tid >> 3, sc8 = tid & 7;
    const size_t koffA = hb + (size_t)sr * 64 + ((sc8 ^ (sr & 7)) << 3);
    const int vr = tid >> 2, vc = tid & 3;
    const size_t voff = hb + (size_t)vr * 1024 + ((vc ^ ((vr >> 1) & 3)) << 3);

    // ---- pass 1: softmax stats over 128-k tiles (8 rounds, bufs @0 / @8192)
    float m2 = -3.0e38f;
    float lacc[4] = {0.f, 0.f, 0.f, 0.f};
#pragma unroll
    for (int s = 0; s < 4; ++s)
        GLL16(Kmu + koffA + s * 2048, &L[s * 2048 + tid * 8]);
    __syncthreads();
    for (int t = 0; t < 8; ++t) {
        SBAR();
        const int tn = (t < 7) ? t + 1 : 7;
        const int nb = (t & 1) ? 0 : 8192;
#pragma unroll
        for (int s = 0; s < 4; ++s)
            GLL16(Kmu + koffA + (size_t)tn * 8192 + s * 2048, &L[nb + s * 2048 + tid * 8]);
        VMCNT(4);
        SBAR();
        const int kb = (t & 1) ? 8192 : 0;
        f32x4 sc[8];
#pragma unroll
        for (int kt = 0; kt < 8; ++kt) sc[kt] = (f32x4){0.f, 0.f, 0.f, 0.f};
        __builtin_amdgcn_s_setprio(1);
#pragma unroll
        for (int kt = 0; kt < 8; ++kt) {
            int row = kt * 16 + q15, ra = kb + (row << 6);
            bf16x8 k0 = *(const bf16x8*)&L[ra + ((g ^ (row & 7)) << 3)];
            bf16x8 k1 = *(const bf16x8*)&L[ra + (((g + 4) ^ (row & 7)) << 3)];
            sc[kt] = __builtin_amdgcn_mfma_f32_16x16x32_bf16(k0, bq0, sc[kt], 0, 0, 0);
            sc[kt] = __builtin_amdgcn_mfma_f32_16x16x32_bf16(k1, bq1, sc[kt], 0, 0, 0);
        }
        __builtin_amdgcn_s_setprio(0);
        float tmx = -3.0e38f;
#pragma unroll
        for (int kt = 0; kt < 8; ++kt)
#pragma unroll
            for (int r = 0; r < 4; ++r) tmx = fmaxf(tmx, sc[kt][r]);
        tmx *= C2E;
        if (tmx > m2 + 8.f) {
            float f = ex2(m2 - tmx);
            lacc[0] *= f; lacc[1] *= f; lacc[2] *= f; lacc[3] *= f;
            m2 = tmx;
        }
#pragma unroll
        for (int kt = 0; kt < 8; ++kt)
#pragma unroll
            for (int r = 0; r < 4; ++r)
                lacc[kt & 3] += ex2(fmaf(sc[kt][r], C2E, -m2));
    }
    __syncthreads();
    float l = (lacc[0] + lacc[1]) + (lacc[2] + lacc[3]);
#pragma unroll
    for (int off = 16; off <= 32; off <<= 1) {
        float mo = __shfl_xor(m2, off), lo = __shfl_xor(l, off);
        float nm = fmaxf(m2, mo);
        l = l * ex2(m2 - nm) + lo * ex2(mo - nm);
        m2 = nm;
    }
    const float M = m2 + lg2(l);

    // ---- pass 2: K and V both double-buffered
    f32x4 accm[4], accd[4], acce[4];
#pragma unroll
    for (int nt = 0; nt < 4; ++nt) {
        accm[nt] = (f32x4){0.f, 0.f, 0.f, 0.f};
        accd[nt] = (f32x4){0.f, 0.f, 0.f, 0.f};
        acce[nt] = (f32x4){0.f, 0.f, 0.f, 0.f};
    }

    GLL16(Kmu + koffA, &L[KB0 + 0    + wv * 512]);
    GLL16(Ksg + koffA, &L[KB0 + 2048 + wv * 512]);
    GLL16(Asq + koffA, &L[KB0 + 4096 + wv * 512]);
    GLL16(Vmu + voff, &L[VB0 + 0    + wv * 512]);
    GLL16(Vsg + voff, &L[VB0 + 2048 + wv * 512]);
    GLL16(Vw2 + voff, &L[VB0 + 4096 + wv * 512]);
    __syncthreads();

    for (int t = 0; t < 32; ++t) {
        SBAR();
        const int tn = (t < 31) ? t + 1 : 31;
        const size_t ka = (size_t)tn << 11;
        const size_t va = (size_t)tn << 5;
        const int nbK = (t & 1) ? KB0 : KB1;
        const int nbV = (t & 1) ? VB0 : VB1;
        GLL16(Kmu + koffA + ka, &L[nbK + 0    + wv * 512]);
        GLL16(Ksg + koffA + ka, &L[nbK + 2048 + wv * 512]);
        GLL16(Asq + koffA + ka, &L[nbK + 4096 + wv * 512]);
        GLL16(Vmu + voff + va,  &L[nbV + 0    + wv * 512]);
        GLL16(Vsg + voff + va,  &L[nbV + 2048 + wv * 512]);
        GLL16(Vw2 + voff + va,  &L[nbV + 4096 + wv * 512]);
        VMCNT(6);
        SBAR();

        const int kb = (t & 1) ? KB1 : KB0;
        const int vb = (t & 1) ? VB1 : VB0;
        f32x4 sc[2], sgc[2];
#pragma unroll
        for (int kt = 0; kt < 2; ++kt) { sc[kt] = (f32x4){0.f,0.f,0.f,0.f}; sgc[kt] = (f32x4){0.f,0.f,0.f,0.f}; }
        __builtin_amdgcn_s_setprio(1);
#pragma unroll
        for (int kt = 0; kt < 2; ++kt) {
            int row = kt * 16 + q15, ra = kb + (row << 6);
            int ca = ((g ^ (row & 7)) << 3), cb = (((g + 4) ^ (row & 7)) << 3);
            sc[kt]  = __builtin_amdgcn_mfma_f32_16x16x32_bf16(*(const bf16x8*)&L[ra + ca],        bq0, sc[kt],  0, 0, 0);
            sc[kt]  = __builtin_amdgcn_mfma_f32_16x16x32_bf16(*(const bf16x8*)&L[ra + cb],        bq1, sc[kt],  0, 0, 0);
            sgc[kt] = __builtin_amdgcn_mfma_f32_16x16x32_bf16(*(const bf16x8*)&L[2048 + ra + ca], b10, sgc[kt], 0, 0, 0);
            sgc[kt] = __builtin_amdgcn_mfma_f32_16x16x32_bf16(*(const bf16x8*)&L[2048 + ra + cb], b11, sgc[kt], 0, 0, 0);
            sgc[kt] = __builtin_amdgcn_mfma_f32_16x16x32_bf16(*(const bf16x8*)&L[4096 + ra + ca], b20, sgc[kt], 0, 0, 0);
            sgc[kt] = __builtin_amdgcn_mfma_f32_16x16x32_bf16(*(const bf16x8*)&L[4096 + ra + cb], b21, sgc[kt], 0, 0, 0);
        }
        __builtin_amdgcn_s_setprio(0);

        float p[8], p2v[8], swv[8];
#pragma unroll
        for (int kt = 0; kt < 2; ++kt)
#pragma unroll
            for (int r = 0; r < 4; ++r) {
                int j = kt * 4 + r;
                float pv = ex2(fmaf(sc[kt][r], C2E, -M));
                float pp = pv * pv;
                float gq = pv - pp;
                p[j] = pv; p2v[j] = pp; swv[j] = gq * gq * sgc[kt][r];
            }
        u32x4 ua  = {cvtpk(p[0], p[1]),     cvtpk(p[2], p[3]),     cvtpk(p[4], p[5]),     cvtpk(p[6], p[7])};
        u32x4 ubv = {cvtpk(p2v[0], p2v[1]), cvtpk(p2v[2], p2v[3]), cvtpk(p2v[4], p2v[5]), cvtpk(p2v[6], p2v[7])};
        u32x4 ucv = {cvtpk(swv[0], swv[1]), cvtpk(swv[2], swv[3]), cvtpk(swv[4], swv[5]), cvtpk(swv[6], swv[7])};
        bf16x8 pa  = *(const bf16x8*)&ua;
        bf16x8 p2a = *(const bf16x8*)&ubv;
        bf16x8 swa = *(const bf16x8*)&ucv;

        __builtin_amdgcn_s_setprio(1);
#pragma unroll
        for (int nt = 0; nt < 4; ++nt) {
            int row = nt * 16 + q15;
            int vi = vb + (row << 5) + ((g ^ ((q15 >> 1) & 3)) << 3);
            accm[nt] = __builtin_amdgcn_mfma_f32_16x16x32_bf16(pa,  *(const bf16x8*)&L[vi],        accm[nt], 0, 0, 0);
            accd[nt] = __builtin_amdgcn_mfma_f32_16x16x32_bf16(p2a, *(const bf16x8*)&L[vi + 2048], accd[nt], 0, 0, 0);
            acce[nt] = __builtin_amdgcn_mfma_f32_16x16x32_bf16(swa, *(const bf16x8*)&L[vi + 4096], acce[nt], 0, 0, 0);
        }
        __builtin_amdgcn_s_setprio(0);
    }

    // ---- epilogue: store bf16 + fused row stats
    const int b_ = bh / 12, h_ = bh % 12;
#pragma unroll
    for (int r = 0; r < 4; ++r) {
        int srow = qt * 64 + wv * 16 + g * 4 + r;
        int n = b_ * 1024 + srow;
        float s1 = 0.f, s2 = 0.f;
#pragma unroll
        for (int nt = 0; nt < 4; ++nt) {
            int d = nt * 16 + q15;
            float mu = accm[nt][r];
            float sg = sp_f(accd[nt][r] + acce[nt][r]);
            size_t o = (size_t)n * E + h_ * 64 + d;
            om[o]  = f2bf(mu);
            osg[o] = f2bf(sg);
            s1 += mu * mu;
            s2 += sg;
        }
#pragma unroll
        for (int off = 1; off < 16; off <<= 1) {
            s1 += __shfl_xor(s1, off);
            s2 += __shfl_xor(s2, off);
        }
        if (q15 == 0) {
            atomicAdd(&armu2[n], s1);
            atomicAdd(&arsg[n], s2);
        }
    }
}

// --------------------------------------------------------------- launch ----
extern "C" void kernel_launch(void* const* d_in, const int* in_sizes, int n_in,
                              void* d_out, int out_size, void* d_ws, size_t ws_size,
                              hipStream_t stream)
{
    const float* mu_in = (const float*)d_in[0];
    const float* sg_in = (const float*)d_in[1];
    const float* wq  = (const float*)d_in[2];
    const float* wqs = (const float*)d_in[3];
    const float* wk  = (const float*)d_in[4];
    const float* wks = (const float*)d_in[5];
    const float* wvp = (const float*)d_in[6];
    const float* wvs = (const float*)d_in[7];
    const float* wo  = (const float*)d_in[8];
    const float* wos = (const float*)d_in[9];

    float* out_mu = (float*)d_out;
    float* out_sg = out_mu + (size_t)NTOK * E;
    float* kl_out = out_mu + 2 * (size_t)NTOK * E;

    float* ws = (float*)d_ws;
    size_t off = 0;
    auto allocf = [&](size_t n) { float* p = ws + off; off += n; return p; };
    float* rmu2  = allocf(NTOK);
    float* rsgs  = allocf(NTOK);
    float* armu2 = allocf(NTOK);
    float* arsg  = allocf(NTOK);
    float* spws  = allocf(4 * E);

    u16* ub = (u16*)(ws + off);
    size_t uoff = 0;
    auto allocu = [&](size_t n) { u16* p = ub + uoff; uoff += n; return p; };
    u16* Xmu    = allocu(BFN);
    u16* Xsg    = allocu(BFN);
    u16* WtAll  = allocu(4 * WFN);
    u16* W2tAll = allocu(4 * WFN);
    u16* QKVB   = allocu(9 * BFN);
    u16* amu_b  = allocu(BFN);
    u16* asg_b  = allocu(BFN);
    (void)ws_size; (void)in_sizes; (void)n_in; (void)out_size;

    hipMemsetAsync(kl_out, 0, 4, stream);
    hipMemsetAsync(armu2, 0, 2 * NTOK * sizeof(float), stream);  // armu2+arsg contiguous
    prep_all<<<4353, 256, 0, stream>>>(mu_in, sg_in, wq, wk, wvp, wo,
                                       wqs, wks, wvs, wos,
                                       Xmu, Xsg, rmu2, rsgs, WtAll, W2tAll,
                                       spws, kl_out);

    linear_qkv<<<1152, 256, 0, stream>>>(Xmu, Xsg, WtAll, W2tAll, spws, rmu2, rsgs, QKVB);

    vdp_attn9<<<768, 256, 0, stream>>>(QKVB + 3 * BFN, QKVB + 4 * BFN, QKVB + 1 * BFN,
                                       QKVB + 0 * BFN, QKVB + 2 * BFN, QKVB + 5 * BFN,
                                       QKVB + 6 * BFN, QKVB + 7 * BFN, QKVB + 8 * BFN,
                                       amu_b, asg_b, armu2, arsg);

    linear_oproj64<<<768, 256, 0, stream>>>(amu_b, asg_b, WtAll + 3 * WFN, W2tAll + 3 * WFN,
                                            spws + 3 * E, armu2, arsg, out_mu, out_sg);
}

// Round 17
// 232.945 us; speedup vs baseline: 1.0130x; 1.0130x over previous
//
#include <hip/hip_runtime.h>
#include <math.h>

#define E 768
#define NTOK 4096  /* BATCH*S */

typedef __attribute__((ext_vector_type(8))) __bf16 bf16x8;
typedef __attribute__((ext_vector_type(4))) float f32x4;
typedef unsigned int u32;
typedef unsigned short u16;
typedef __attribute__((ext_vector_type(4))) u32 u32x4;

#define BFN ((size_t)NTOK * E)
#define WFN ((size_t)E * E)
#define QSC 1.4901161193847656e-08f   /* 2^-26 */
#define C2E 0.18033688011112042f      /* 0.125 * log2(e) */

__device__ __forceinline__ float sp_f(float x) {
    return fmaxf(x, 0.f) + log1pf(__expf(-fabsf(x)));
}
__device__ __forceinline__ u16 f2bf(float f) {
    u32 u = __float_as_uint(f);
    u += 0x7fffu + ((u >> 16) & 1u);
    return (u16)(u >> 16);
}
__device__ __forceinline__ u32 pk2(float a, float b) {
    return (u32)f2bf(a) | ((u32)f2bf(b) << 16);
}
__device__ __forceinline__ u32 cvtpk(float a, float b) {
    u32 r; asm("v_cvt_pk_bf16_f32 %0, %1, %2" : "=v"(r) : "v"(a), "v"(b)); return r;
}
__device__ __forceinline__ float ex2(float x) {
    float r; asm("v_exp_f32 %0, %1" : "=v"(r) : "v"(x)); return r;
}
__device__ __forceinline__ float lg2(float x) {
    float r; asm("v_log_f32 %0, %1" : "=v"(r) : "v"(x)); return r;
}
__device__ __forceinline__ float bfl(u32 u) { return __uint_as_float(u << 16); }
__device__ __forceinline__ float bfh(u32 u) { return __uint_as_float(u & 0xffff0000u); }

#define GLL16(gp, lp) __builtin_amdgcn_global_load_lds( \
    (const __attribute__((address_space(1))) u32*)(gp), \
    (__attribute__((address_space(3))) u32*)(lp), 16, 0, 0)

#define SBAR() do { __builtin_amdgcn_sched_barrier(0); \
                    __builtin_amdgcn_s_barrier(); \
                    __builtin_amdgcn_sched_barrier(0); } while (0)
#define VMCNT(N) do { asm volatile("s_waitcnt vmcnt(" #N ")" ::: "memory"); \
                      __builtin_amdgcn_sched_barrier(0); } while (0)

// ----------------------------------------------------------- prep (fused) --
// blocks [0,2048): fp32->bf16 conv + input row stats (2 rows/block)
// blocks [2048,4352): weight transpose+square, FUSED KL partial (each W
//   element read exactly once here); rem==0 block per matrix adds sigma terms
// block 4352: softplus(w_sigma) table
__global__ __launch_bounds__(256) void prep_all(
    const float* __restrict__ mu_in, const float* __restrict__ sg_in,
    const float* __restrict__ wq, const float* __restrict__ wk,
    const float* __restrict__ wvp, const float* __restrict__ wo,
    const float* __restrict__ wqs, const float* __restrict__ wks,
    const float* __restrict__ wvs, const float* __restrict__ wos,
    u16* __restrict__ Xmu, u16* __restrict__ Xsg,
    float* __restrict__ rmu2, float* __restrict__ rsg,
    u16* __restrict__ WtAll, u16* __restrict__ W2tAll,
    float* __restrict__ spws, float* __restrict__ kl_out)
{
    __shared__ float T[32][33];
    __shared__ float r1[4], r2[4];
    const int b = blockIdx.x, tid = threadIdx.x;

    if (b < 2048) {
        const int half = tid >> 7;
        const int n = b * 2 + half;
        const int t2 = tid & 127;
        float s1 = 0.f, s2 = 0.f;
        if (t2 < 96) {
            size_t o = (size_t)n * E + t2 * 8;
            float4 a0 = *(const float4*)(mu_in + o), a1 = *(const float4*)(mu_in + o + 4);
            float4 b0 = *(const float4*)(sg_in + o), b1 = *(const float4*)(sg_in + o + 4);
            *(uint4*)(Xmu + o) = make_uint4(pk2(a0.x, a0.y), pk2(a0.z, a0.w), pk2(a1.x, a1.y), pk2(a1.z, a1.w));
            *(uint4*)(Xsg + o) = make_uint4(pk2(b0.x, b0.y), pk2(b0.z, b0.w), pk2(b1.x, b1.y), pk2(b1.z, b1.w));
            s1 = a0.x*a0.x + a0.y*a0.y + a0.z*a0.z + a0.w*a0.w + a1.x*a1.x + a1.y*a1.y + a1.z*a1.z + a1.w*a1.w;
            s2 = b0.x + b0.y + b0.z + b0.w + b1.x + b1.y + b1.z + b1.w;
        }
        for (int off = 32; off; off >>= 1) {
            s1 += __shfl_xor(s1, off);
            s2 += __shfl_xor(s2, off);
        }
        if ((tid & 63) == 0) { r1[tid >> 6] = s1; r2[tid >> 6] = s2; }
        __syncthreads();
        if (t2 == 0) {
            rmu2[n] = r1[half * 2] + r1[half * 2 + 1];
            rsg[n]  = r2[half * 2] + r2[half * 2 + 1];
        }
    } else if (b < 4352) {
        const int b2 = b - 2048;
        const int z = b2 / 576, rem = b2 - z * 576;
        const float* W = (z == 0) ? wq : (z == 1) ? wk : (z == 2) ? wvp : wo;
        u16* Wt  = WtAll  + (size_t)z * WFN;
        u16* W2t = W2tAll + (size_t)z * WFN;
        const int j0 = (rem % 24) * 32, k0 = (rem / 24) * 32;
        const int r = tid >> 3, c = (tid & 7) * 4;
        float4 v = *(const float4*)(W + (size_t)(k0 + r) * E + j0 + c);
        // KL partial: every W element passes through here exactly once
        const float cw = 100.f / ((float)E * (float)E);
        float ka = (v.x * v.x + v.y * v.y + v.z * v.z + v.w * v.w) * cw;
        if (rem == 0) {
            const float* sv = (z == 0) ? wqs : (z == 1) ? wks : (z == 2) ? wvs : wos;
            for (int i = tid; i < E; i += 256) {
                float x = sv[i];
                ka += (-x + sp_f(x) * 100.f) * (1.f / (float)E);
            }
            if (b == 2048 && tid == 0) ka += 4.f * (logf(0.01f) - 1.f);
        }
        T[r][c] = v.x; T[r][c + 1] = v.y; T[r][c + 2] = v.z; T[r][c + 3] = v.w;
        __syncthreads();
        const int j = tid >> 3, kc = (tid & 7) * 4;
        float w0 = T[kc][j], w1 = T[kc + 1][j], w2 = T[kc + 2][j], w3 = T[kc + 3][j];
        size_t o = (size_t)(j0 + j) * E + k0 + kc;
        *(uint2*)(Wt + o) = make_uint2(pk2(w0, w1), pk2(w2, w3));
        const float s = 1.f / 768.f;
        *(uint2*)(W2t + o) = make_uint2(pk2(w0 * w0 * s, w1 * w1 * s), pk2(w2 * w2 * s, w3 * w3 * s));
        // KL reduce + one atomic per block
        for (int off = 32; off; off >>= 1) ka += __shfl_xor(ka, off);
        if ((tid & 63) == 0) r1[tid >> 6] = ka;
        __syncthreads();
        if (tid == 0) atomicAdd(kl_out, 0.5f * (r1[0] + r1[1] + r1[2] + r1[3]));
    } else {
        for (int i = tid; i < 4 * E; i += 256) {
            const float* src;
            int j;
            if (i < E)            { src = wqs; j = i; }
            else if (i < 2 * E)   { src = wks; j = i - E; }
            else if (i < 3 * E)   { src = wvs; j = i - 2 * E; }
            else                  { src = wos; j = i - 3 * E; }
            spws[i] = sp_f(src[j]);
        }
    }
}

// --------------------------------- QKV linear (round-9/15 proven) ---------
// 128x64 tile, BK=32, NBUF=2, 48KB LDS, 3 blocks/CU, XCD m-fastest.
__global__ __launch_bounds__(256, 3) void linear_qkv(
    const u16* __restrict__ Am, const u16* __restrict__ As,
    const u16* __restrict__ Wt, const u16* __restrict__ W2t,
    const float* __restrict__ spws, const float* __restrict__ rmu2, const float* __restrict__ rsg,
    u16* __restrict__ QKVB)
{
    __shared__ __align__(16) u16 L[24576];

    const int wgid = blockIdx.x;
    const int xcd = wgid & 7, local = wgid >> 3;
    const int m_blk = xcd * 4 + (local & 3);
    const int n_blk = local >> 2;
    const int m0 = m_blk * 128, col0 = n_blk * 64;
    const int tid = threadIdx.x, wv = tid >> 6, lane = tid & 63;
    const int g = lane >> 4, q15 = lane & 15;

    const u16* sp_[6];
    {
        const int rA = tid >> 2, cA = tid & 3;
        const int rB = 64 + rA;
        const int csA = (cA ^ ((rA >> 1) & 3)) << 3;
        const int csB = (cA ^ ((rB >> 1) & 3)) << 3;
        sp_[0] = Am  + (size_t)(m0 + rA) * E + csA;
        sp_[1] = Am  + (size_t)(m0 + rB) * E + csB;
        sp_[2] = As  + (size_t)(m0 + rA) * E + csA;
        sp_[3] = As  + (size_t)(m0 + rB) * E + csB;
        sp_[4] = Wt  + (size_t)(col0 + rA) * E + csA;
        sp_[5] = W2t + (size_t)(col0 + rA) * E + csA;
    }

    f32x4 acc1[2][4], acc2[2][4];
#pragma unroll
    for (int mt = 0; mt < 2; ++mt)
#pragma unroll
        for (int nt = 0; nt < 4; ++nt) {
            acc1[mt][nt] = (f32x4){0.f, 0.f, 0.f, 0.f};
            acc2[mt][nt] = (f32x4){0.f, 0.f, 0.f, 0.f};
        }

#pragma unroll
    for (int j = 0; j < 6; ++j)
        GLL16(sp_[j], &L[j * 2048 + tid * 8]);

    for (int t = 0; t < 24; ++t) {
        SBAR();
        const int tn = (t < 23) ? t + 1 : 23;
        const int nb = ((t & 1) ^ 1) * 12288;
#pragma unroll
        for (int j = 0; j < 6; ++j)
            GLL16(sp_[j] + tn * 32, &L[nb + j * 2048 + tid * 8]);
        VMCNT(6);
        SBAR();
        const int cb = (t & 1) * 12288;
        bf16x8 am[2], asg[2];
#pragma unroll
        for (int mt = 0; mt < 2; ++mt) {
            int r = wv * 32 + mt * 16 + q15;
            int c = (g ^ ((r >> 1) & 3)) << 3;
            am[mt]  = *(const bf16x8*)&L[cb + r * 32 + c];
            asg[mt] = *(const bf16x8*)&L[cb + 4096 + r * 32 + c];
        }
        __builtin_amdgcn_s_setprio(1);
#pragma unroll
        for (int nt = 0; nt < 4; ++nt) {
            int rb = nt * 16 + q15;
            int c = (g ^ ((rb >> 1) & 3)) << 3;
            bf16x8 bw = *(const bf16x8*)&L[cb + 8192 + rb * 32 + c];
            bf16x8 b2 = *(const bf16x8*)&L[cb + 10240 + rb * 32 + c];
            acc1[0][nt] = __builtin_amdgcn_mfma_f32_16x16x32_bf16(am[0], bw, acc1[0][nt], 0, 0, 0);
            acc1[1][nt] = __builtin_amdgcn_mfma_f32_16x16x32_bf16(am[1], bw, acc1[1][nt], 0, 0, 0);
            acc2[0][nt] = __builtin_amdgcn_mfma_f32_16x16x32_bf16(asg[0], b2, acc2[0][nt], 0, 0, 0);
            acc2[1][nt] = __builtin_amdgcn_mfma_f32_16x16x32_bf16(asg[1], b2, acc2[1][nt], 0, 0, 0);
        }
        __builtin_amdgcn_s_setprio(0);
    }
    __syncthreads();

    const float inv2 = 1.f / (768.f * 768.f), invd = 1.f / 768.f;
    float rr[2][4];
#pragma unroll
    for (int mt = 0; mt < 2; ++mt)
#pragma unroll
        for (int r = 0; r < 4; ++r) {
            int row = m0 + wv * 32 + mt * 16 + g * 4 + r;
            rr[mt][r] = rmu2[row] * inv2 + rsg[row] * invd;
        }

    const int proj = n_blk / 12, h = n_blk % 12;
    float sgv[2][4][4];
#pragma unroll
    for (int mt = 0; mt < 2; ++mt)
#pragma unroll
        for (int nt = 0; nt < 4; ++nt)
#pragma unroll
            for (int r = 0; r < 4; ++r) {
                int col = col0 + nt * 16 + q15;
                sgv[mt][nt][r] = sp_f(acc2[mt][nt][r] + rr[mt][r] * spws[col]);
            }
    const int bb = m0 >> 10;
    if (proj < 2) {
        const int s0 = (m0 & 1023);
        const int sl = tid >> 1, hh = tid & 1;
        size_t gbase = ((size_t)(bb * 12 + h) << 16) + ((size_t)(s0 + sl) << 6) + hh * 32;
#pragma unroll
        for (int a = 0; a < 3; ++a) {
            __syncthreads();
#pragma unroll
            for (int mt = 0; mt < 2; ++mt)
#pragma unroll
                for (int nt = 0; nt < 4; ++nt)
#pragma unroll
                    for (int r = 0; r < 4; ++r) {
                        float mu = acc1[mt][nt][r], sg = sgv[mt][nt][r];
                        float v = (a == 0) ? mu : (a == 1) ? sg :
                                  (proj == 0 ? (mu * mu + sg) * QSC : mu * mu * QSC);
                        L[(wv * 32 + mt * 16 + g * 4 + r) * 72 + nt * 16 + q15] = f2bf(v);
                    }
            __syncthreads();
            u16* dst = QKVB + (size_t)(proj * 3 + a) * BFN;
#pragma unroll
            for (int j = 0; j < 4; ++j)
                *(uint4*)(dst + gbase + j * 8) = *(const uint4*)&L[sl * 72 + hh * 32 + j * 8];
        }
    } else {
        const int s0 = m0 & 1023;
#pragma unroll
        for (int a = 0; a < 3; ++a) {
            __syncthreads();
#pragma unroll
            for (int mt = 0; mt < 2; ++mt)
#pragma unroll
                for (int nt = 0; nt < 4; ++nt)
#pragma unroll
                    for (int r = 0; r < 4; ++r) {
                        float mu = acc1[mt][nt][r], sg = sgv[mt][nt][r];
                        float v = (a == 0) ? mu : (a == 1) ? sg * 0.0009765625f : mu * mu + sg;
                        L[(nt * 16 + q15) * 136 + wv * 32 + g * 8 + mt * 4 + r] = f2bf(v);
                    }
            __syncthreads();
            const int d = tid >> 2, sc = (tid & 3) * 32;
            u16* dst = QKVB + (size_t)(6 + a) * BFN;
            size_t ga = ((size_t)((bb * 12 + h) * 64 + d) << 10) + s0 + sc;
            *(uint4*)(dst + ga)      = *(const uint4*)&L[d * 136 + sc];
            *(uint4*)(dst + ga + 8)  = *(const uint4*)&L[d * 136 + sc + 8];
            *(uint4*)(dst + ga + 16) = *(const uint4*)&L[d * 136 + sc + 16];
            *(uint4*)(dst + ga + 24) = *(const uint4*)&L[d * 136 + sc + 24];
        }
    }
}

// ------------------------- O-proj: 64x64 tile, grid 768 = 3 blocks/CU ------
__global__ __launch_bounds__(256, 3) void linear_oproj64(
    const u16* __restrict__ Am, const u16* __restrict__ As,
    const u16* __restrict__ Wt, const u16* __restrict__ W2t,
    const float* __restrict__ spws, const float* __restrict__ rmu2, const float* __restrict__ rsg,
    float* __restrict__ mu_out, float* __restrict__ sg_out)
{
    __shared__ __align__(16) u16 L[16384];   // 32KB = 2 x 8192

    const int wgid = blockIdx.x;             // 768 = 8 xcd x (8 m x 12 n)
    const int xcd = wgid & 7, local = wgid >> 3;
    const int m_blk = xcd * 8 + (local & 7); // m fastest within chunk
    const int n_blk = local >> 3;            // [0,12)
    const int m0 = m_blk * 64, col0 = n_blk * 64;
    const int tid = threadIdx.x, wv = tid >> 6, lane = tid & 63;
    const int g = lane >> 4, q15 = lane & 15;

    const u16* sp_[4];
    {
        const int r = tid >> 2, c = tid & 3;
        const int cs = (c ^ ((r >> 1) & 3)) << 3;
        sp_[0] = Am  + (size_t)(m0 + r) * E + cs;
        sp_[1] = As  + (size_t)(m0 + r) * E + cs;
        sp_[2] = Wt  + (size_t)(col0 + r) * E + cs;
        sp_[3] = W2t + (size_t)(col0 + r) * E + cs;
    }

    f32x4 acc1[4], acc2[4];
#pragma unroll
    for (int nt = 0; nt < 4; ++nt) {
        acc1[nt] = (f32x4){0.f, 0.f, 0.f, 0.f};
        acc2[nt] = (f32x4){0.f, 0.f, 0.f, 0.f};
    }

#pragma unroll
    for (int j = 0; j < 4; ++j)
        GLL16(sp_[j], &L[j * 2048 + tid * 8]);

    for (int t = 0; t < 24; ++t) {
        SBAR();
        const int tn = (t < 23) ? t + 1 : 23;
        const int nb = ((t & 1) ^ 1) * 8192;
#pragma unroll
        for (int j = 0; j < 4; ++j)
            GLL16(sp_[j] + tn * 32, &L[nb + j * 2048 + tid * 8]);
        VMCNT(4);
        SBAR();
        const int cb = (t & 1) * 8192;
        int rA = wv * 16 + q15;
        int cA = (g ^ ((rA >> 1) & 3)) << 3;
        bf16x8 am  = *(const bf16x8*)&L[cb + rA * 32 + cA];
        bf16x8 asg = *(const bf16x8*)&L[cb + 2048 + rA * 32 + cA];
        __builtin_amdgcn_s_setprio(1);
#pragma unroll
        for (int nt = 0; nt < 4; ++nt) {
            int rb = nt * 16 + q15;
            int c = (g ^ ((rb >> 1) & 3)) << 3;
            bf16x8 bw = *(const bf16x8*)&L[cb + 4096 + rb * 32 + c];
            bf16x8 b2 = *(const bf16x8*)&L[cb + 6144 + rb * 32 + c];
            acc1[nt] = __builtin_amdgcn_mfma_f32_16x16x32_bf16(am,  bw, acc1[nt], 0, 0, 0);
            acc2[nt] = __builtin_amdgcn_mfma_f32_16x16x32_bf16(asg, b2, acc2[nt], 0, 0, 0);
        }
        __builtin_amdgcn_s_setprio(0);
    }

    const float inv2 = 1.f / (768.f * 768.f), invd = 1.f / 768.f;
#pragma unroll
    for (int r = 0; r < 4; ++r) {
        int row = m0 + wv * 16 + g * 4 + r;
        float rr = rmu2[row] * inv2 + rsg[row] * invd;
#pragma unroll
        for (int nt = 0; nt < 4; ++nt) {
            int col = col0 + nt * 16 + q15;
            float mu = acc1[nt][r];
            float sg = sp_f(sp_f(acc2[nt][r] + rr * spws[col]));
            mu_out[(size_t)row * E + col] = mu;
            sg_out[(size_t)row * E + col] = sg;
        }
    }
}

// ------------------------------------------------------------- attention ---
// v9 (round-15 proven): pass 1 = 128-k tiles (8 rounds); pass 2 = K+V dbuf;
// epilogue fuses row stats via 16-lane shfl reduce + atomicAdd.
#define KB0 0
#define KB1 6144
#define VB0 12288
#define VB1 18432
__global__ __launch_bounds__(256, 3) void vdp_attn9(
    const u16* __restrict__ Kmu, const u16* __restrict__ Ksg, const u16* __restrict__ Asq,
    const u16* __restrict__ Qmu, const u16* __restrict__ Q1v, const u16* __restrict__ Q2v,
    const u16* __restrict__ Vmu, const u16* __restrict__ Vsg, const u16* __restrict__ Vw2,
    u16* __restrict__ om, u16* __restrict__ osg,
    float* __restrict__ armu2, float* __restrict__ arsg)
{
    __shared__ __align__(16) u16 L[24576];   // 48KB

    const int wgid = blockIdx.x;                  // 768 = 48bh x 16qt
    const int seq = (wgid & 7) * 96 + (wgid >> 3);
    const int bh = seq >> 4, qt = seq & 15;
    const int tid = threadIdx.x, wv = tid >> 6, lane = tid & 63;
    const int g = lane >> 4, q15 = lane & 15;
    const size_t hb = (size_t)bh << 16;

    const size_t qoff = hb + (size_t)((qt * 64 + wv * 16 + q15) << 6) + g * 8;
    bf16x8 bq0 = *(const bf16x8*)(Qmu + qoff), bq1 = *(const bf16x8*)(Qmu + qoff + 32);
    bf16x8 b10 = *(const bf16x8*)(Q1v + qoff), b11 = *(const bf16x8*)(Q1v + qoff + 32);
    bf16x8 b20 = *(const bf16x8*)(Q2v + qoff), b21 = *(const bf16x8*)(Q2v + qoff + 32);

    const int sr = tid >> 3, sc8 = tid & 7;
    const size_t koffA = hb + (size_t)sr * 64 + ((sc8 ^ (sr & 7)) << 3);
    const int vr = tid >> 2, vc = tid & 3;
    const size_t voff = hb + (size_t)vr * 1024 + ((vc ^ ((vr >> 1) & 3)) << 3);

    // ---- pass 1: softmax stats over 128-k tiles (8 rounds, bufs @0 / @8192)
    float m2 = -3.0e38f;
    float lacc[4] = {0.f, 0.f, 0.f, 0.f};
#pragma unroll
    for (int s = 0; s < 4; ++s)
        GLL16(Kmu + koffA + s * 2048, &L[s * 2048 + tid * 8]);
    __syncthreads();
    for (int t = 0; t < 8; ++t) {
        SBAR();
        const int tn = (t < 7) ? t + 1 : 7;
        const int nb = (t & 1) ? 0 : 8192;
#pragma unroll
        for (int s = 0; s < 4; ++s)
            GLL16(Kmu + koffA + (size_t)tn * 8192 + s * 2048, &L[nb + s * 2048 + tid * 8]);
        VMCNT(4);
        SBAR();
        const int kb = (t & 1) ? 8192 : 0;
        f32x4 sc[8];
#pragma unroll
        for (int kt = 0; kt < 8; ++kt) sc[kt] = (f32x4){0.f, 0.f, 0.f, 0.f};
        __builtin_amdgcn_s_setprio(1);
#pragma unroll
        for (int kt = 0; kt < 8; ++kt) {
            int row = kt * 16 + q15, ra = kb + (row << 6);
            bf16x8 k0 = *(const bf16x8*)&L[ra + ((g ^ (row & 7)) << 3)];
            bf16x8 k1 = *(const bf16x8*)&L[ra + (((g + 4) ^ (row & 7)) << 3)];
            sc[kt] = __builtin_amdgcn_mfma_f32_16x16x32_bf16(k0, bq0, sc[kt], 0, 0, 0);
            sc[kt] = __builtin_amdgcn_mfma_f32_16x16x32_bf16(k1, bq1, sc[kt], 0, 0, 0);
        }
        __builtin_amdgcn_s_setprio(0);
        float tmx = -3.0e38f;
#pragma unroll
        for (int kt = 0; kt < 8; ++kt)
#pragma unroll
            for (int r = 0; r < 4; ++r) tmx = fmaxf(tmx, sc[kt][r]);
        tmx *= C2E;
        if (tmx > m2 + 8.f) {
            float f = ex2(m2 - tmx);
            lacc[0] *= f; lacc[1] *= f; lacc[2] *= f; lacc[3] *= f;
            m2 = tmx;
        }
#pragma unroll
        for (int kt = 0; kt < 8; ++kt)
#pragma unroll
            for (int r = 0; r < 4; ++r)
                lacc[kt & 3] += ex2(fmaf(sc[kt][r], C2E, -m2));
    }
    __syncthreads();
    float l = (lacc[0] + lacc[1]) + (lacc[2] + lacc[3]);
#pragma unroll
    for (int off = 16; off <= 32; off <<= 1) {
        float mo = __shfl_xor(m2, off), lo = __shfl_xor(l, off);
        float nm = fmaxf(m2, mo);
        l = l * ex2(m2 - nm) + lo * ex2(mo - nm);
        m2 = nm;
    }
    const float M = m2 + lg2(l);

    // ---- pass 2: K and V both double-buffered
    f32x4 accm[4], accd[4], acce[4];
#pragma unroll
    for (int nt = 0; nt < 4; ++nt) {
        accm[nt] = (f32x4){0.f, 0.f, 0.f, 0.f};
        accd[nt] = (f32x4){0.f, 0.f, 0.f, 0.f};
        acce[nt] = (f32x4){0.f, 0.f, 0.f, 0.f};
    }

    GLL16(Kmu + koffA, &L[KB0 + 0    + wv * 512]);
    GLL16(Ksg + koffA, &L[KB0 + 2048 + wv * 512]);
    GLL16(Asq + koffA, &L[KB0 + 4096 + wv * 512]);
    GLL16(Vmu + voff, &L[VB0 + 0    + wv * 512]);
    GLL16(Vsg + voff, &L[VB0 + 2048 + wv * 512]);
    GLL16(Vw2 + voff, &L[VB0 + 4096 + wv * 512]);
    __syncthreads();

    for (int t = 0; t < 32; ++t) {
        SBAR();
        const int tn = (t < 31) ? t + 1 : 31;
        const size_t ka = (size_t)tn << 11;
        const size_t va = (size_t)tn << 5;
        const int nbK = (t & 1) ? KB0 : KB1;
        const int nbV = (t & 1) ? VB0 : VB1;
        GLL16(Kmu + koffA + ka, &L[nbK + 0    + wv * 512]);
        GLL16(Ksg + koffA + ka, &L[nbK + 2048 + wv * 512]);
        GLL16(Asq + koffA + ka, &L[nbK + 4096 + wv * 512]);
        GLL16(Vmu + voff + va,  &L[nbV + 0    + wv * 512]);
        GLL16(Vsg + voff + va,  &L[nbV + 2048 + wv * 512]);
        GLL16(Vw2 + voff + va,  &L[nbV + 4096 + wv * 512]);
        VMCNT(6);
        SBAR();

        const int kb = (t & 1) ? KB1 : KB0;
        const int vb = (t & 1) ? VB1 : VB0;
        f32x4 sc[2], sgc[2];
#pragma unroll
        for (int kt = 0; kt < 2; ++kt) { sc[kt] = (f32x4){0.f,0.f,0.f,0.f}; sgc[kt] = (f32x4){0.f,0.f,0.f,0.f}; }
        __builtin_amdgcn_s_setprio(1);
#pragma unroll
        for (int kt = 0; kt < 2; ++kt) {
            int row = kt * 16 + q15, ra = kb + (row << 6);
            int ca = ((g ^ (row & 7)) << 3), cb = (((g + 4) ^ (row & 7)) << 3);
            sc[kt]  = __builtin_amdgcn_mfma_f32_16x16x32_bf16(*(const bf16x8*)&L[ra + ca],        bq0, sc[kt],  0, 0, 0);
            sc[kt]  = __builtin_amdgcn_mfma_f32_16x16x32_bf16(*(const bf16x8*)&L[ra + cb],        bq1, sc[kt],  0, 0, 0);
            sgc[kt] = __builtin_amdgcn_mfma_f32_16x16x32_bf16(*(const bf16x8*)&L[2048 + ra + ca], b10, sgc[kt], 0, 0, 0);
            sgc[kt] = __builtin_amdgcn_mfma_f32_16x16x32_bf16(*(const bf16x8*)&L[2048 + ra + cb], b11, sgc[kt], 0, 0, 0);
            sgc[kt] = __builtin_amdgcn_mfma_f32_16x16x32_bf16(*(const bf16x8*)&L[4096 + ra + ca], b20, sgc[kt], 0, 0, 0);
            sgc[kt] = __builtin_amdgcn_mfma_f32_16x16x32_bf16(*(const bf16x8*)&L[4096 + ra + cb], b21, sgc[kt], 0, 0, 0);
        }
        __builtin_amdgcn_s_setprio(0);

        float p[8], p2v[8], swv[8];
#pragma unroll
        for (int kt = 0; kt < 2; ++kt)
#pragma unroll
            for (int r = 0; r < 4; ++r) {
                int j = kt * 4 + r;
                float pv = ex2(fmaf(sc[kt][r], C2E, -M));
                float pp = pv * pv;
                float gq = pv - pp;
                p[j] = pv; p2v[j] = pp; swv[j] = gq * gq * sgc[kt][r];
            }
        u32x4 ua  = {cvtpk(p[0], p[1]),     cvtpk(p[2], p[3]),     cvtpk(p[4], p[5]),     cvtpk(p[6], p[7])};
        u32x4 ubv = {cvtpk(p2v[0], p2v[1]), cvtpk(p2v[2], p2v[3]), cvtpk(p2v[4], p2v[5]), cvtpk(p2v[6], p2v[7])};
        u32x4 ucv = {cvtpk(swv[0], swv[1]), cvtpk(swv[2], swv[3]), cvtpk(swv[4], swv[5]), cvtpk(swv[6], swv[7])};
        bf16x8 pa  = *(const bf16x8*)&ua;
        bf16x8 p2a = *(const bf16x8*)&ubv;
        bf16x8 swa = *(const bf16x8*)&ucv;

        __builtin_amdgcn_s_setprio(1);
#pragma unroll
        for (int nt = 0; nt < 4; ++nt) {
            int row = nt * 16 + q15;
            int vi = vb + (row << 5) + ((g ^ ((q15 >> 1) & 3)) << 3);
            accm[nt] = __builtin_amdgcn_mfma_f32_16x16x32_bf16(pa,  *(const bf16x8*)&L[vi],        accm[nt], 0, 0, 0);
            accd[nt] = __builtin_amdgcn_mfma_f32_16x16x32_bf16(p2a, *(const bf16x8*)&L[vi + 2048], accd[nt], 0, 0, 0);
            acce[nt] = __builtin_amdgcn_mfma_f32_16x16x32_bf16(swa, *(const bf16x8*)&L[vi + 4096], acce[nt], 0, 0, 0);
        }
        __builtin_amdgcn_s_setprio(0);
    }

    // ---- epilogue: store bf16 + fused row stats
    const int b_ = bh / 12, h_ = bh % 12;
#pragma unroll
    for (int r = 0; r < 4; ++r) {
        int srow = qt * 64 + wv * 16 + g * 4 + r;
        int n = b_ * 1024 + srow;
        float s1 = 0.f, s2 = 0.f;
#pragma unroll
        for (int nt = 0; nt < 4; ++nt) {
            int d = nt * 16 + q15;
            float mu = accm[nt][r];
            float sg = sp_f(accd[nt][r] + acce[nt][r]);
            size_t o = (size_t)n * E + h_ * 64 + d;
            om[o]  = f2bf(mu);
            osg[o] = f2bf(sg);
            s1 += mu * mu;
            s2 += sg;
        }
#pragma unroll
        for (int off = 1; off < 16; off <<= 1) {
            s1 += __shfl_xor(s1, off);
            s2 += __shfl_xor(s2, off);
        }
        if (q15 == 0) {
            atomicAdd(&armu2[n], s1);
            atomicAdd(&arsg[n], s2);
        }
    }
}

// --------------------------------------------------------------- launch ----
extern "C" void kernel_launch(void* const* d_in, const int* in_sizes, int n_in,
                              void* d_out, int out_size, void* d_ws, size_t ws_size,
                              hipStream_t stream)
{
    const float* mu_in = (const float*)d_in[0];
    const float* sg_in = (const float*)d_in[1];
    const float* wq  = (const float*)d_in[2];
    const float* wqs = (const float*)d_in[3];
    const float* wk  = (const float*)d_in[4];
    const float* wks = (const float*)d_in[5];
    const float* wvp = (const float*)d_in[6];
    const float* wvs = (const float*)d_in[7];
    const float* wo  = (const float*)d_in[8];
    const float* wos = (const float*)d_in[9];

    float* out_mu = (float*)d_out;
    float* out_sg = out_mu + (size_t)NTOK * E;
    float* kl_out = out_mu + 2 * (size_t)NTOK * E;

    float* ws = (float*)d_ws;
    size_t off = 0;
    auto allocf = [&](size_t n) { float* p = ws + off; off += n; return p; };
    float* rmu2  = allocf(NTOK);
    float* rsgs  = allocf(NTOK);
    float* armu2 = allocf(NTOK);
    float* arsg  = allocf(NTOK);
    float* spws  = allocf(4 * E);

    u16* ub = (u16*)(ws + off);
    size_t uoff = 0;
    auto allocu = [&](size_t n) { u16* p = ub + uoff; uoff += n; return p; };
    u16* Xmu    = allocu(BFN);
    u16* Xsg    = allocu(BFN);
    u16* WtAll  = allocu(4 * WFN);
    u16* W2tAll = allocu(4 * WFN);
    u16* QKVB   = allocu(9 * BFN);
    u16* amu_b  = allocu(BFN);
    u16* asg_b  = allocu(BFN);
    (void)ws_size; (void)in_sizes; (void)n_in; (void)out_size;

    hipMemsetAsync(kl_out, 0, 4, stream);
    hipMemsetAsync(armu2, 0, 2 * NTOK * sizeof(float), stream);  // armu2+arsg contiguous
    prep_all<<<4353, 256, 0, stream>>>(mu_in, sg_in, wq, wk, wvp, wo,
                                       wqs, wks, wvs, wos,
                                       Xmu, Xsg, rmu2, rsgs, WtAll, W2tAll,
                                       spws, kl_out);

    linear_qkv<<<1152, 256, 0, stream>>>(Xmu, Xsg, WtAll, W2tAll, spws, rmu2, rsgs, QKVB);

    vdp_attn9<<<768, 256, 0, stream>>>(QKVB + 3 * BFN, QKVB + 4 * BFN, QKVB + 1 * BFN,
                                       QKVB + 0 * BFN, QKVB + 2 * BFN, QKVB + 5 * BFN,
                                       QKVB + 6 * BFN, QKVB + 7 * BFN, QKVB + 8 * BFN,
                                       amu_b, asg_b, armu2, arsg);

    linear_oproj64<<<768, 256, 0, stream>>>(amu_b, asg_b, WtAll + 3 * WFN, W2tAll + 3 * WFN,
                                            spws + 3 * E, armu2, arsg, out_mu, out_sg);
}

// Round 18
// 221.856 us; speedup vs baseline: 1.0636x; 1.0500x over previous
//
#include <hip/hip_runtime.h>
#include <math.h>

#define E 768
#define NTOK 4096  /* BATCH*S */

typedef __attribute__((ext_vector_type(8))) __bf16 bf16x8;
typedef __attribute__((ext_vector_type(4))) float f32x4;
typedef unsigned int u32;
typedef unsigned short u16;
typedef __attribute__((ext_vector_type(4))) u32 u32x4;

#define BFN ((size_t)NTOK * E)
#define WFN ((size_t)E * E)
#define QSC 1.4901161193847656e-08f   /* 2^-26 */
#define C2E 0.18033688011112042f      /* 0.125 * log2(e) */

__device__ __forceinline__ float sp_f(float x) {
    return fmaxf(x, 0.f) + log1pf(__expf(-fabsf(x)));
}
__device__ __forceinline__ u16 f2bf(float f) {
    u32 u = __float_as_uint(f);
    u += 0x7fffu + ((u >> 16) & 1u);
    return (u16)(u >> 16);
}
__device__ __forceinline__ u32 pk2(float a, float b) {
    return (u32)f2bf(a) | ((u32)f2bf(b) << 16);
}
__device__ __forceinline__ u32 cvtpk(float a, float b) {
    u32 r; asm("v_cvt_pk_bf16_f32 %0, %1, %2" : "=v"(r) : "v"(a), "v"(b)); return r;
}
__device__ __forceinline__ float ex2(float x) {
    float r; asm("v_exp_f32 %0, %1" : "=v"(r) : "v"(x)); return r;
}
__device__ __forceinline__ float lg2(float x) {
    float r; asm("v_log_f32 %0, %1" : "=v"(r) : "v"(x)); return r;
}
__device__ __forceinline__ float bfl(u32 u) { return __uint_as_float(u << 16); }
__device__ __forceinline__ float bfh(u32 u) { return __uint_as_float(u & 0xffff0000u); }

#define GLL16(gp, lp) __builtin_amdgcn_global_load_lds( \
    (const __attribute__((address_space(1))) u32*)(gp), \
    (__attribute__((address_space(3))) u32*)(lp), 16, 0, 0)

#define SBAR() do { __builtin_amdgcn_sched_barrier(0); \
                    __builtin_amdgcn_s_barrier(); \
                    __builtin_amdgcn_sched_barrier(0); } while (0)
#define VMCNT(N) do { asm volatile("s_waitcnt vmcnt(" #N ")" ::: "memory"); \
                      __builtin_amdgcn_sched_barrier(0); } while (0)

// ----------------------------------------------------------- prep (fused) --
__global__ __launch_bounds__(256) void prep_all(
    const float* __restrict__ mu_in, const float* __restrict__ sg_in,
    const float* __restrict__ wq, const float* __restrict__ wk,
    const float* __restrict__ wvp, const float* __restrict__ wo,
    const float* __restrict__ wqs, const float* __restrict__ wks,
    const float* __restrict__ wvs, const float* __restrict__ wos,
    u16* __restrict__ Xmu, u16* __restrict__ Xsg,
    float* __restrict__ rmu2, float* __restrict__ rsg,
    u16* __restrict__ WtAll, u16* __restrict__ W2tAll,
    float* __restrict__ spws, float* __restrict__ kl_out)
{
    __shared__ float T[32][33];
    __shared__ float r1[4], r2[4];
    const int b = blockIdx.x, tid = threadIdx.x;

    if (b < 2048) {
        const int half = tid >> 7;
        const int n = b * 2 + half;
        const int t2 = tid & 127;
        float s1 = 0.f, s2 = 0.f;
        if (t2 < 96) {
            size_t o = (size_t)n * E + t2 * 8;
            float4 a0 = *(const float4*)(mu_in + o), a1 = *(const float4*)(mu_in + o + 4);
            float4 b0 = *(const float4*)(sg_in + o), b1 = *(const float4*)(sg_in + o + 4);
            *(uint4*)(Xmu + o) = make_uint4(pk2(a0.x, a0.y), pk2(a0.z, a0.w), pk2(a1.x, a1.y), pk2(a1.z, a1.w));
            *(uint4*)(Xsg + o) = make_uint4(pk2(b0.x, b0.y), pk2(b0.z, b0.w), pk2(b1.x, b1.y), pk2(b1.z, b1.w));
            s1 = a0.x*a0.x + a0.y*a0.y + a0.z*a0.z + a0.w*a0.w + a1.x*a1.x + a1.y*a1.y + a1.z*a1.z + a1.w*a1.w;
            s2 = b0.x + b0.y + b0.z + b0.w + b1.x + b1.y + b1.z + b1.w;
        }
        for (int off = 32; off; off >>= 1) {
            s1 += __shfl_xor(s1, off);
            s2 += __shfl_xor(s2, off);
        }
        if ((tid & 63) == 0) { r1[tid >> 6] = s1; r2[tid >> 6] = s2; }
        __syncthreads();
        if (t2 == 0) {
            rmu2[n] = r1[half * 2] + r1[half * 2 + 1];
            rsg[n]  = r2[half * 2] + r2[half * 2 + 1];
        }
    } else if (b < 4352) {
        const int b2 = b - 2048;
        const int z = b2 / 576, rem = b2 - z * 576;
        const float* W = (z == 0) ? wq : (z == 1) ? wk : (z == 2) ? wvp : wo;
        u16* Wt  = WtAll  + (size_t)z * WFN;
        u16* W2t = W2tAll + (size_t)z * WFN;
        const int j0 = (rem % 24) * 32, k0 = (rem / 24) * 32;
        const int r = tid >> 3, c = (tid & 7) * 4;
        float4 v = *(const float4*)(W + (size_t)(k0 + r) * E + j0 + c);
        T[r][c] = v.x; T[r][c + 1] = v.y; T[r][c + 2] = v.z; T[r][c + 3] = v.w;
        __syncthreads();
        const int j = tid >> 3, kc = (tid & 7) * 4;
        float w0 = T[kc][j], w1 = T[kc + 1][j], w2 = T[kc + 2][j], w3 = T[kc + 3][j];
        size_t o = (size_t)(j0 + j) * E + k0 + kc;
        *(uint2*)(Wt + o) = make_uint2(pk2(w0, w1), pk2(w2, w3));
        const float s = 1.f / 768.f;
        *(uint2*)(W2t + o) = make_uint2(pk2(w0 * w0 * s, w1 * w1 * s), pk2(w2 * w2 * s, w3 * w3 * s));
    } else if (b < 4864) {
        const int gid = (b - 4352) * 256 + tid;
        const int gsz = 512 * 256;
        float acc = 0.f;
        const float cw = 100.f / ((float)E * (float)E);
#pragma unroll
        for (int mm = 0; mm < 4; ++mm) {
            const float* w  = (mm == 0) ? wq  : (mm == 1) ? wk  : (mm == 2) ? wvp : wo;
            const float* sv = (mm == 0) ? wqs : (mm == 1) ? wks : (mm == 2) ? wvs : wos;
            for (int i = gid; i < E * E; i += gsz) { float x = w[i]; acc += x * x * cw; }
            for (int i = gid; i < E; i += gsz) { float x = sv[i]; acc += (-x + sp_f(x) * 100.f) * (1.f / (float)E); }
        }
        if (b == 4352 && tid == 0) acc += 4.f * (logf(0.01f) - 1.f);
        for (int off = 32; off; off >>= 1) acc += __shfl_xor(acc, off);
        if ((tid & 63) == 0) r1[tid >> 6] = acc;
        __syncthreads();
        if (tid == 0) atomicAdd(kl_out, 0.5f * (r1[0] + r1[1] + r1[2] + r1[3]));
    } else {
        for (int i = tid; i < 4 * E; i += 256) {
            const float* src;
            int j;
            if (i < E)            { src = wqs; j = i; }
            else if (i < 2 * E)   { src = wks; j = i - E; }
            else if (i < 3 * E)   { src = wvs; j = i - 2 * E; }
            else                  { src = wos; j = i - 3 * E; }
            spws[i] = sp_f(src[j]);
        }
    }
}

// --------------------------------- linear (BK=32 bf16 MFMA, 128x64 tile) ---
// NBUF=2 double-buffer (round-9 proven). 48KB LDS, 3 blocks/CU. XCD-chunked
// m-fastest ordering for W-panel / A-slice L2 residency.
template<int MODE, int NBUF>
__global__ __launch_bounds__(256, 3) void linear_fused(
    const u16* __restrict__ Am, const u16* __restrict__ As,
    const u16* __restrict__ Wt, const u16* __restrict__ W2t,
    const float* __restrict__ spws, const float* __restrict__ rmu2, const float* __restrict__ rsg,
    float* __restrict__ mu_out, float* __restrict__ sg_out, u16* __restrict__ QKVB)
{
    __shared__ __align__(16) u16 L[NBUF * 12288];

    const int wgid = blockIdx.x;
    const int xcd = wgid & 7, local = wgid >> 3;
    const int m_blk = xcd * 4 + (local & 3);        // m fastest within chunk
    const int n_blk = local >> 2;
    const int m0 = m_blk * 128, col0 = n_blk * 64;
    const int tid = threadIdx.x, wv = tid >> 6, lane = tid & 63;
    const int g = lane >> 4, q15 = lane & 15;

    const u16* sp_[6];
    {
        const int rA = tid >> 2, cA = tid & 3;
        const int rB = 64 + rA;
        const int csA = (cA ^ ((rA >> 1) & 3)) << 3;
        const int csB = (cA ^ ((rB >> 1) & 3)) << 3;
        sp_[0] = Am  + (size_t)(m0 + rA) * E + csA;
        sp_[1] = Am  + (size_t)(m0 + rB) * E + csB;
        sp_[2] = As  + (size_t)(m0 + rA) * E + csA;
        sp_[3] = As  + (size_t)(m0 + rB) * E + csB;
        sp_[4] = Wt  + (size_t)(col0 + rA) * E + csA;
        sp_[5] = W2t + (size_t)(col0 + rA) * E + csA;
    }

    f32x4 acc1[2][4], acc2[2][4];
#pragma unroll
    for (int mt = 0; mt < 2; ++mt)
#pragma unroll
        for (int nt = 0; nt < 4; ++nt) {
            acc1[mt][nt] = (f32x4){0.f, 0.f, 0.f, 0.f};
            acc2[mt][nt] = (f32x4){0.f, 0.f, 0.f, 0.f};
        }

#pragma unroll
    for (int j = 0; j < 6; ++j)
        GLL16(sp_[j], &L[j * 2048 + tid * 8]);

    for (int t = 0; t < 24; ++t) {
        SBAR();
        const int tn = (t < 23) ? t + 1 : 23;
        const int nb = ((t & 1) ^ 1) * 12288;
#pragma unroll
        for (int j = 0; j < 6; ++j)
            GLL16(sp_[j] + tn * 32, &L[nb + j * 2048 + tid * 8]);
        VMCNT(6);
        SBAR();
        const int cb = (t & 1) * 12288;
        bf16x8 am[2], asg[2];
#pragma unroll
        for (int mt = 0; mt < 2; ++mt) {
            int r = wv * 32 + mt * 16 + q15;
            int c = (g ^ ((r >> 1) & 3)) << 3;
            am[mt]  = *(const bf16x8*)&L[cb + r * 32 + c];
            asg[mt] = *(const bf16x8*)&L[cb + 4096 + r * 32 + c];
        }
        __builtin_amdgcn_s_setprio(1);
#pragma unroll
        for (int nt = 0; nt < 4; ++nt) {
            int rb = nt * 16 + q15;
            int c = (g ^ ((rb >> 1) & 3)) << 3;
            bf16x8 bw = *(const bf16x8*)&L[cb + 8192 + rb * 32 + c];
            bf16x8 b2 = *(const bf16x8*)&L[cb + 10240 + rb * 32 + c];
            acc1[0][nt] = __builtin_amdgcn_mfma_f32_16x16x32_bf16(am[0], bw, acc1[0][nt], 0, 0, 0);
            acc1[1][nt] = __builtin_amdgcn_mfma_f32_16x16x32_bf16(am[1], bw, acc1[1][nt], 0, 0, 0);
            acc2[0][nt] = __builtin_amdgcn_mfma_f32_16x16x32_bf16(asg[0], b2, acc2[0][nt], 0, 0, 0);
            acc2[1][nt] = __builtin_amdgcn_mfma_f32_16x16x32_bf16(asg[1], b2, acc2[1][nt], 0, 0, 0);
        }
        __builtin_amdgcn_s_setprio(0);
    }
    __syncthreads();

    const float inv2 = 1.f / (768.f * 768.f), invd = 1.f / 768.f;
    float rr[2][4];
#pragma unroll
    for (int mt = 0; mt < 2; ++mt)
#pragma unroll
        for (int r = 0; r < 4; ++r) {
            int row = m0 + wv * 32 + mt * 16 + g * 4 + r;
            rr[mt][r] = rmu2[row] * inv2 + rsg[row] * invd;
        }

    if (MODE == 0) {
#pragma unroll
        for (int mt = 0; mt < 2; ++mt)
#pragma unroll
            for (int nt = 0; nt < 4; ++nt)
#pragma unroll
                for (int r = 0; r < 4; ++r) {
                    int row = m0 + wv * 32 + mt * 16 + g * 4 + r;
                    int col = col0 + nt * 16 + q15;
                    float mu = acc1[mt][nt][r];
                    float sg = sp_f(sp_f(acc2[mt][nt][r] + rr[mt][r] * spws[col]));
                    mu_out[(size_t)row * E + col] = mu;
                    sg_out[(size_t)row * E + col] = sg;
                }
    } else {
        const int proj = n_blk / 12, h = n_blk % 12;
        float sgv[2][4][4];
#pragma unroll
        for (int mt = 0; mt < 2; ++mt)
#pragma unroll
            for (int nt = 0; nt < 4; ++nt)
#pragma unroll
                for (int r = 0; r < 4; ++r) {
                    int col = col0 + nt * 16 + q15;
                    sgv[mt][nt][r] = sp_f(acc2[mt][nt][r] + rr[mt][r] * spws[col]);
                }
        const int bb = m0 >> 10;
        if (proj < 2) {
            // coalesced [bh][s][d] store via LDS transpose (pad 72):
            // each thread owns a contiguous 32-u16 run (4 x uint4).
            const int s0 = (m0 & 1023);
            const int sl = tid >> 1, hh = tid & 1;
            size_t gbase = ((size_t)(bb * 12 + h) << 16) + ((size_t)(s0 + sl) << 6) + hh * 32;
#pragma unroll
            for (int a = 0; a < 3; ++a) {
                __syncthreads();
#pragma unroll
                for (int mt = 0; mt < 2; ++mt)
#pragma unroll
                    for (int nt = 0; nt < 4; ++nt)
#pragma unroll
                        for (int r = 0; r < 4; ++r) {
                            float mu = acc1[mt][nt][r], sg = sgv[mt][nt][r];
                            float v = (a == 0) ? mu : (a == 1) ? sg :
                                      (proj == 0 ? (mu * mu + sg) * QSC : mu * mu * QSC);
                            L[(wv * 32 + mt * 16 + g * 4 + r) * 72 + nt * 16 + q15] = f2bf(v);
                        }
                __syncthreads();
                u16* dst = QKVB + (size_t)(proj * 3 + a) * BFN;
#pragma unroll
                for (int j = 0; j < 4; ++j)
                    *(uint4*)(dst + gbase + j * 8) = *(const uint4*)&L[sl * 72 + hh * 32 + j * 8];
            }
        } else {
            // V: [bh][d][s], s permuted in 32-blocks (slot g*8+mt*4+r)
            const int s0 = m0 & 1023;
#pragma unroll
            for (int a = 0; a < 3; ++a) {
                __syncthreads();
#pragma unroll
                for (int mt = 0; mt < 2; ++mt)
#pragma unroll
                    for (int nt = 0; nt < 4; ++nt)
#pragma unroll
                        for (int r = 0; r < 4; ++r) {
                            float mu = acc1[mt][nt][r], sg = sgv[mt][nt][r];
                            float v = (a == 0) ? mu : (a == 1) ? sg * 0.0009765625f : mu * mu + sg;
                            L[(nt * 16 + q15) * 136 + wv * 32 + g * 8 + mt * 4 + r] = f2bf(v);
                        }
                __syncthreads();
                const int d = tid >> 2, sc = (tid & 3) * 32;
                u16* dst = QKVB + (size_t)(6 + a) * BFN;
                size_t ga = ((size_t)((bb * 12 + h) * 64 + d) << 10) + s0 + sc;
                *(uint4*)(dst + ga)      = *(const uint4*)&L[d * 136 + sc];
                *(uint4*)(dst + ga + 8)  = *(const uint4*)&L[d * 136 + sc + 8];
                *(uint4*)(dst + ga + 16) = *(const uint4*)&L[d * 136 + sc + 16];
                *(uint4*)(dst + ga + 24) = *(const uint4*)&L[d * 136 + sc + 24];
            }
        }
    }
}

// ------------------------------------------------------------- attention ---
// v9: pass 1 = 128-k tiles (8 barrier rounds, 16KB x2 bufs); pass 2 = the
// proven v8 K+V double-buffered loop; epilogue fuses row stats (Σmu², Σsg)
// via 16-lane shfl reduce + one atomicAdd per row per head.
#define KB0 0
#define KB1 6144
#define VB0 12288
#define VB1 18432
__global__ __launch_bounds__(256, 3) void vdp_attn9(
    const u16* __restrict__ Kmu, const u16* __restrict__ Ksg, const u16* __restrict__ Asq,
    const u16* __restrict__ Qmu, const u16* __restrict__ Q1v, const u16* __restrict__ Q2v,
    const u16* __restrict__ Vmu, const u16* __restrict__ Vsg, const u16* __restrict__ Vw2,
    u16* __restrict__ om, u16* __restrict__ osg,
    float* __restrict__ armu2, float* __restrict__ arsg)
{
    __shared__ __align__(16) u16 L[24576];   // 48KB

    const int wgid = blockIdx.x;                  // 768 = 48bh x 16qt
    const int seq = (wgid & 7) * 96 + (wgid >> 3);
    const int bh = seq >> 4, qt = seq & 15;
    const int tid = threadIdx.x, wv = tid >> 6, lane = tid & 63;
    const int g = lane >> 4, q15 = lane & 15;
    const size_t hb = (size_t)bh << 16;

    const size_t qoff = hb + (size_t)((qt * 64 + wv * 16 + q15) << 6) + g * 8;
    bf16x8 bq0 = *(const bf16x8*)(Qmu + qoff), bq1 = *(const bf16x8*)(Qmu + qoff + 32);
    bf16x8 b10 = *(const bf16x8*)(Q1v + qoff), b11 = *(const bf16x8*)(Q1v + qoff + 32);
    bf16x8 b20 = *(const bf16x8*)(Q2v + qoff), b21 = *(const bf16x8*)(Q2v + qoff + 32);

    const int sr = tid >> 3, sc8 = tid & 7;
    const size_t koffA = hb + (size_t)sr * 64 + ((sc8 ^ (sr & 7)) << 3);
    const int vr = tid >> 2, vc = tid & 3;
    const size_t voff = hb + (size_t)vr * 1024 + ((vc ^ ((vr >> 1) & 3)) << 3);

    // ---- pass 1: softmax stats over 128-k tiles (8 rounds, bufs @0 / @8192)
    float m2 = -3.0e38f;
    float lacc[4] = {0.f, 0.f, 0.f, 0.f};
#pragma unroll
    for (int s = 0; s < 4; ++s)
        GLL16(Kmu + koffA + s * 2048, &L[s * 2048 + tid * 8]);
    __syncthreads();
    for (int t = 0; t < 8; ++t) {
        SBAR();
        const int tn = (t < 7) ? t + 1 : 7;
        const int nb = (t & 1) ? 0 : 8192;
#pragma unroll
        for (int s = 0; s < 4; ++s)
            GLL16(Kmu + koffA + (size_t)tn * 8192 + s * 2048, &L[nb + s * 2048 + tid * 8]);
        VMCNT(4);
        SBAR();
        const int kb = (t & 1) ? 8192 : 0;
        f32x4 sc[8];
#pragma unroll
        for (int kt = 0; kt < 8; ++kt) sc[kt] = (f32x4){0.f, 0.f, 0.f, 0.f};
        __builtin_amdgcn_s_setprio(1);
#pragma unroll
        for (int kt = 0; kt < 8; ++kt) {
            int row = kt * 16 + q15, ra = kb + (row << 6);
            bf16x8 k0 = *(const bf16x8*)&L[ra + ((g ^ (row & 7)) << 3)];
            bf16x8 k1 = *(const bf16x8*)&L[ra + (((g + 4) ^ (row & 7)) << 3)];
            sc[kt] = __builtin_amdgcn_mfma_f32_16x16x32_bf16(k0, bq0, sc[kt], 0, 0, 0);
            sc[kt] = __builtin_amdgcn_mfma_f32_16x16x32_bf16(k1, bq1, sc[kt], 0, 0, 0);
        }
        __builtin_amdgcn_s_setprio(0);
        float tmx = -3.0e38f;
#pragma unroll
        for (int kt = 0; kt < 8; ++kt)
#pragma unroll
            for (int r = 0; r < 4; ++r) tmx = fmaxf(tmx, sc[kt][r]);
        tmx *= C2E;
        if (tmx > m2 + 8.f) {
            float f = ex2(m2 - tmx);
            lacc[0] *= f; lacc[1] *= f; lacc[2] *= f; lacc[3] *= f;
            m2 = tmx;
        }
#pragma unroll
        for (int kt = 0; kt < 8; ++kt)
#pragma unroll
            for (int r = 0; r < 4; ++r)
                lacc[kt & 3] += ex2(fmaf(sc[kt][r], C2E, -m2));
    }
    __syncthreads();
    float l = (lacc[0] + lacc[1]) + (lacc[2] + lacc[3]);
#pragma unroll
    for (int off = 16; off <= 32; off <<= 1) {
        float mo = __shfl_xor(m2, off), lo = __shfl_xor(l, off);
        float nm = fmaxf(m2, mo);
        l = l * ex2(m2 - nm) + lo * ex2(mo - nm);
        m2 = nm;
    }
    const float M = m2 + lg2(l);

    // ---- pass 2: K and V both double-buffered (v8 proven)
    f32x4 accm[4], accd[4], acce[4];
#pragma unroll
    for (int nt = 0; nt < 4; ++nt) {
        accm[nt] = (f32x4){0.f, 0.f, 0.f, 0.f};
        accd[nt] = (f32x4){0.f, 0.f, 0.f, 0.f};
        acce[nt] = (f32x4){0.f, 0.f, 0.f, 0.f};
    }

    GLL16(Kmu + koffA, &L[KB0 + 0    + wv * 512]);
    GLL16(Ksg + koffA, &L[KB0 + 2048 + wv * 512]);
    GLL16(Asq + koffA, &L[KB0 + 4096 + wv * 512]);
    GLL16(Vmu + voff, &L[VB0 + 0    + wv * 512]);
    GLL16(Vsg + voff, &L[VB0 + 2048 + wv * 512]);
    GLL16(Vw2 + voff, &L[VB0 + 4096 + wv * 512]);
    __syncthreads();

    for (int t = 0; t < 32; ++t) {
        SBAR();                                   // buf[cur^1] free to overwrite
        const int tn = (t < 31) ? t + 1 : 31;
        const size_t ka = (size_t)tn << 11;
        const size_t va = (size_t)tn << 5;
        const int nbK = (t & 1) ? KB0 : KB1;
        const int nbV = (t & 1) ? VB0 : VB1;
        GLL16(Kmu + koffA + ka, &L[nbK + 0    + wv * 512]);
        GLL16(Ksg + koffA + ka, &L[nbK + 2048 + wv * 512]);
        GLL16(Asq + koffA + ka, &L[nbK + 4096 + wv * 512]);
        GLL16(Vmu + voff + va,  &L[nbV + 0    + wv * 512]);
        GLL16(Vsg + voff + va,  &L[nbV + 2048 + wv * 512]);
        GLL16(Vw2 + voff + va,  &L[nbV + 4096 + wv * 512]);
        VMCNT(6);                                 // K(t),V(t) landed (mine)
        SBAR();                                   // ... for everyone

        const int kb = (t & 1) ? KB1 : KB0;
        const int vb = (t & 1) ? VB1 : VB0;
        f32x4 sc[2], sgc[2];
#pragma unroll
        for (int kt = 0; kt < 2; ++kt) { sc[kt] = (f32x4){0.f,0.f,0.f,0.f}; sgc[kt] = (f32x4){0.f,0.f,0.f,0.f}; }
        __builtin_amdgcn_s_setprio(1);
#pragma unroll
        for (int kt = 0; kt < 2; ++kt) {
            int row = kt * 16 + q15, ra = kb + (row << 6);
            int ca = ((g ^ (row & 7)) << 3), cb = (((g + 4) ^ (row & 7)) << 3);
            sc[kt]  = __builtin_amdgcn_mfma_f32_16x16x32_bf16(*(const bf16x8*)&L[ra + ca],        bq0, sc[kt],  0, 0, 0);
            sc[kt]  = __builtin_amdgcn_mfma_f32_16x16x32_bf16(*(const bf16x8*)&L[ra + cb],        bq1, sc[kt],  0, 0, 0);
            sgc[kt] = __builtin_amdgcn_mfma_f32_16x16x32_bf16(*(const bf16x8*)&L[2048 + ra + ca], b10, sgc[kt], 0, 0, 0);
            sgc[kt] = __builtin_amdgcn_mfma_f32_16x16x32_bf16(*(const bf16x8*)&L[2048 + ra + cb], b11, sgc[kt], 0, 0, 0);
            sgc[kt] = __builtin_amdgcn_mfma_f32_16x16x32_bf16(*(const bf16x8*)&L[4096 + ra + ca], b20, sgc[kt], 0, 0, 0);
            sgc[kt] = __builtin_amdgcn_mfma_f32_16x16x32_bf16(*(const bf16x8*)&L[4096 + ra + cb], b21, sgc[kt], 0, 0, 0);
        }
        __builtin_amdgcn_s_setprio(0);

        float p[8], p2v[8], swv[8];
#pragma unroll
        for (int kt = 0; kt < 2; ++kt)
#pragma unroll
            for (int r = 0; r < 4; ++r) {
                int j = kt * 4 + r;
                float pv = ex2(fmaf(sc[kt][r], C2E, -M));
                float pp = pv * pv;
                float gq = pv - pp;
                p[j] = pv; p2v[j] = pp; swv[j] = gq * gq * sgc[kt][r];
            }
        u32x4 ua  = {cvtpk(p[0], p[1]),     cvtpk(p[2], p[3]),     cvtpk(p[4], p[5]),     cvtpk(p[6], p[7])};
        u32x4 ubv = {cvtpk(p2v[0], p2v[1]), cvtpk(p2v[2], p2v[3]), cvtpk(p2v[4], p2v[5]), cvtpk(p2v[6], p2v[7])};
        u32x4 ucv = {cvtpk(swv[0], swv[1]), cvtpk(swv[2], swv[3]), cvtpk(swv[4], swv[5]), cvtpk(swv[6], swv[7])};
        bf16x8 pa  = *(const bf16x8*)&ua;
        bf16x8 p2a = *(const bf16x8*)&ubv;
        bf16x8 swa = *(const bf16x8*)&ucv;

        __builtin_amdgcn_s_setprio(1);
#pragma unroll
        for (int nt = 0; nt < 4; ++nt) {
            int row = nt * 16 + q15;
            int vi = vb + (row << 5) + ((g ^ ((q15 >> 1) & 3)) << 3);
            accm[nt] = __builtin_amdgcn_mfma_f32_16x16x32_bf16(pa,  *(const bf16x8*)&L[vi],        accm[nt], 0, 0, 0);
            accd[nt] = __builtin_amdgcn_mfma_f32_16x16x32_bf16(p2a, *(const bf16x8*)&L[vi + 2048], accd[nt], 0, 0, 0);
            acce[nt] = __builtin_amdgcn_mfma_f32_16x16x32_bf16(swa, *(const bf16x8*)&L[vi + 4096], acce[nt], 0, 0, 0);
        }
        __builtin_amdgcn_s_setprio(0);
    }

    // ---- epilogue: store bf16 + fused row stats (per-row shfl reduce + atomic)
    const int b_ = bh / 12, h_ = bh % 12;
#pragma unroll
    for (int r = 0; r < 4; ++r) {
        int srow = qt * 64 + wv * 16 + g * 4 + r;
        int n = b_ * 1024 + srow;
        float s1 = 0.f, s2 = 0.f;
#pragma unroll
        for (int nt = 0; nt < 4; ++nt) {
            int d = nt * 16 + q15;
            float mu = accm[nt][r];
            float sg = sp_f(accd[nt][r] + acce[nt][r]);
            size_t o = (size_t)n * E + h_ * 64 + d;
            om[o]  = f2bf(mu);
            osg[o] = f2bf(sg);
            s1 += mu * mu;
            s2 += sg;
        }
#pragma unroll
        for (int off = 1; off < 16; off <<= 1) {
            s1 += __shfl_xor(s1, off);
            s2 += __shfl_xor(s2, off);
        }
        if (q15 == 0) {
            atomicAdd(&armu2[n], s1);
            atomicAdd(&arsg[n], s2);
        }
    }
}

// --------------------------------------------------------------- launch ----
extern "C" void kernel_launch(void* const* d_in, const int* in_sizes, int n_in,
                              void* d_out, int out_size, void* d_ws, size_t ws_size,
                              hipStream_t stream)
{
    const float* mu_in = (const float*)d_in[0];
    const float* sg_in = (const float*)d_in[1];
    const float* wq  = (const float*)d_in[2];
    const float* wqs = (const float*)d_in[3];
    const float* wk  = (const float*)d_in[4];
    const float* wks = (const float*)d_in[5];
    const float* wvp = (const float*)d_in[6];
    const float* wvs = (const float*)d_in[7];
    const float* wo  = (const float*)d_in[8];
    const float* wos = (const float*)d_in[9];

    float* out_mu = (float*)d_out;
    float* out_sg = out_mu + (size_t)NTOK * E;
    float* kl_out = out_mu + 2 * (size_t)NTOK * E;

    float* ws = (float*)d_ws;
    size_t off = 0;
    auto allocf = [&](size_t n) { float* p = ws + off; off += n; return p; };
    float* rmu2  = allocf(NTOK);
    float* rsgs  = allocf(NTOK);
    float* armu2 = allocf(NTOK);
    float* arsg  = allocf(NTOK);
    float* spws  = allocf(4 * E);

    u16* ub = (u16*)(ws + off);
    size_t uoff = 0;
    auto allocu = [&](size_t n) { u16* p = ub + uoff; uoff += n; return p; };
    u16* Xmu    = allocu(BFN);
    u16* Xsg    = allocu(BFN);
    u16* WtAll  = allocu(4 * WFN);
    u16* W2tAll = allocu(4 * WFN);
    u16* QKVB   = allocu(9 * BFN);
    u16* amu_b  = allocu(BFN);
    u16* asg_b  = allocu(BFN);
    (void)ws_size; (void)in_sizes; (void)n_in; (void)out_size;

    hipMemsetAsync(kl_out, 0, 4, stream);
    hipMemsetAsync(armu2, 0, 2 * NTOK * sizeof(float), stream);  // armu2+arsg contiguous
    prep_all<<<4865, 256, 0, stream>>>(mu_in, sg_in, wq, wk, wvp, wo,
                                       wqs, wks, wvs, wos,
                                       Xmu, Xsg, rmu2, rsgs, WtAll, W2tAll,
                                       spws, kl_out);

    linear_fused<1, 2><<<1152, 256, 0, stream>>>(Xmu, Xsg, WtAll, W2tAll, spws, rmu2, rsgs,
                                                 nullptr, nullptr, QKVB);

    vdp_attn9<<<768, 256, 0, stream>>>(QKVB + 3 * BFN, QKVB + 4 * BFN, QKVB + 1 * BFN,
                                       QKVB + 0 * BFN, QKVB + 2 * BFN, QKVB + 5 * BFN,
                                       QKVB + 6 * BFN, QKVB + 7 * BFN, QKVB + 8 * BFN,
                                       amu_b, asg_b, armu2, arsg);

    linear_fused<0, 2><<<384, 256, 0, stream>>>(amu_b, asg_b, WtAll + 3 * WFN, W2tAll + 3 * WFN,
                                                spws + 3 * E, armu2, arsg,
                                                out_mu, out_sg, nullptr);
}

// Round 19
// 221.625 us; speedup vs baseline: 1.0647x; 1.0010x over previous
//
#include <hip/hip_runtime.h>
#include <math.h>

#define E 768
#define NTOK 4096  /* BATCH*S */

typedef __attribute__((ext_vector_type(8))) __bf16 bf16x8;
typedef __attribute__((ext_vector_type(4))) float f32x4;
typedef unsigned int u32;
typedef unsigned short u16;
typedef __attribute__((ext_vector_type(4))) u32 u32x4;

#define BFN ((size_t)NTOK * E)
#define WFN ((size_t)E * E)
#define QSC 1.4901161193847656e-08f   /* 2^-26 */
#define C2E 0.18033688011112042f      /* 0.125 * log2(e) */

__device__ __forceinline__ float sp_f(float x) {
    return fmaxf(x, 0.f) + log1pf(__expf(-fabsf(x)));
}
__device__ __forceinline__ u16 f2bf(float f) {
    u32 u = __float_as_uint(f);
    u += 0x7fffu + ((u >> 16) & 1u);
    return (u16)(u >> 16);
}
__device__ __forceinline__ u32 pk2(float a, float b) {
    return (u32)f2bf(a) | ((u32)f2bf(b) << 16);
}
__device__ __forceinline__ u32 cvtpk(float a, float b) {
    u32 r; asm("v_cvt_pk_bf16_f32 %0, %1, %2" : "=v"(r) : "v"(a), "v"(b)); return r;
}
__device__ __forceinline__ float ex2(float x) {
    float r; asm("v_exp_f32 %0, %1" : "=v"(r) : "v"(x)); return r;
}
__device__ __forceinline__ float lg2(float x) {
    float r; asm("v_log_f32 %0, %1" : "=v"(r) : "v"(x)); return r;
}
__device__ __forceinline__ float bfl(u32 u) { return __uint_as_float(u << 16); }
__device__ __forceinline__ float bfh(u32 u) { return __uint_as_float(u & 0xffff0000u); }

#define GLL16(gp, lp) __builtin_amdgcn_global_load_lds( \
    (const __attribute__((address_space(1))) u32*)(gp), \
    (__attribute__((address_space(3))) u32*)(lp), 16, 0, 0)

#define SBAR() do { __builtin_amdgcn_sched_barrier(0); \
                    __builtin_amdgcn_s_barrier(); \
                    __builtin_amdgcn_sched_barrier(0); } while (0)
#define VMCNT(N) do { asm volatile("s_waitcnt vmcnt(" #N ")" ::: "memory"); \
                      __builtin_amdgcn_sched_barrier(0); } while (0)

// ----------------------------------------------------------- prep (fused) --
__global__ __launch_bounds__(256) void prep_all(
    const float* __restrict__ mu_in, const float* __restrict__ sg_in,
    const float* __restrict__ wq, const float* __restrict__ wk,
    const float* __restrict__ wvp, const float* __restrict__ wo,
    const float* __restrict__ wqs, const float* __restrict__ wks,
    const float* __restrict__ wvs, const float* __restrict__ wos,
    u16* __restrict__ Xmu, u16* __restrict__ Xsg,
    float* __restrict__ rmu2, float* __restrict__ rsg,
    u16* __restrict__ WtAll, u16* __restrict__ W2tAll,
    float* __restrict__ spws, float* __restrict__ kl_out)
{
    __shared__ float T[32][33];
    __shared__ float r1[4], r2[4];
    const int b = blockIdx.x, tid = threadIdx.x;

    if (b < 2048) {
        const int half = tid >> 7;
        const int n = b * 2 + half;
        const int t2 = tid & 127;
        float s1 = 0.f, s2 = 0.f;
        if (t2 < 96) {
            size_t o = (size_t)n * E + t2 * 8;
            float4 a0 = *(const float4*)(mu_in + o), a1 = *(const float4*)(mu_in + o + 4);
            float4 b0 = *(const float4*)(sg_in + o), b1 = *(const float4*)(sg_in + o + 4);
            *(uint4*)(Xmu + o) = make_uint4(pk2(a0.x, a0.y), pk2(a0.z, a0.w), pk2(a1.x, a1.y), pk2(a1.z, a1.w));
            *(uint4*)(Xsg + o) = make_uint4(pk2(b0.x, b0.y), pk2(b0.z, b0.w), pk2(b1.x, b1.y), pk2(b1.z, b1.w));
            s1 = a0.x*a0.x + a0.y*a0.y + a0.z*a0.z + a0.w*a0.w + a1.x*a1.x + a1.y*a1.y + a1.z*a1.z + a1.w*a1.w;
            s2 = b0.x + b0.y + b0.z + b0.w + b1.x + b1.y + b1.z + b1.w;
        }
        for (int off = 32; off; off >>= 1) {
            s1 += __shfl_xor(s1, off);
            s2 += __shfl_xor(s2, off);
        }
        if ((tid & 63) == 0) { r1[tid >> 6] = s1; r2[tid >> 6] = s2; }
        __syncthreads();
        if (t2 == 0) {
            rmu2[n] = r1[half * 2] + r1[half * 2 + 1];
            rsg[n]  = r2[half * 2] + r2[half * 2 + 1];
        }
    } else if (b < 4352) {
        const int b2 = b - 2048;
        const int z = b2 / 576, rem = b2 - z * 576;
        const float* W = (z == 0) ? wq : (z == 1) ? wk : (z == 2) ? wvp : wo;
        u16* Wt  = WtAll  + (size_t)z * WFN;
        u16* W2t = W2tAll + (size_t)z * WFN;
        const int j0 = (rem % 24) * 32, k0 = (rem / 24) * 32;
        const int r = tid >> 3, c = (tid & 7) * 4;
        float4 v = *(const float4*)(W + (size_t)(k0 + r) * E + j0 + c);
        T[r][c] = v.x; T[r][c + 1] = v.y; T[r][c + 2] = v.z; T[r][c + 3] = v.w;
        __syncthreads();
        const int j = tid >> 3, kc = (tid & 7) * 4;
        float w0 = T[kc][j], w1 = T[kc + 1][j], w2 = T[kc + 2][j], w3 = T[kc + 3][j];
        size_t o = (size_t)(j0 + j) * E + k0 + kc;
        *(uint2*)(Wt + o) = make_uint2(pk2(w0, w1), pk2(w2, w3));
        const float s = 1.f / 768.f;
        *(uint2*)(W2t + o) = make_uint2(pk2(w0 * w0 * s, w1 * w1 * s), pk2(w2 * w2 * s, w3 * w3 * s));
    } else if (b < 4864) {
        const int gid = (b - 4352) * 256 + tid;
        const int gsz = 512 * 256;
        float acc = 0.f;
        const float cw = 100.f / ((float)E * (float)E);
#pragma unroll
        for (int mm = 0; mm < 4; ++mm) {
            const float* w  = (mm == 0) ? wq  : (mm == 1) ? wk  : (mm == 2) ? wvp : wo;
            const float* sv = (mm == 0) ? wqs : (mm == 1) ? wks : (mm == 2) ? wvs : wos;
            for (int i = gid; i < E * E; i += gsz) { float x = w[i]; acc += x * x * cw; }
            for (int i = gid; i < E; i += gsz) { float x = sv[i]; acc += (-x + sp_f(x) * 100.f) * (1.f / (float)E); }
        }
        if (b == 4352 && tid == 0) acc += 4.f * (logf(0.01f) - 1.f);
        for (int off = 32; off; off >>= 1) acc += __shfl_xor(acc, off);
        if ((tid & 63) == 0) r1[tid >> 6] = acc;
        __syncthreads();
        if (tid == 0) atomicAdd(kl_out, 0.5f * (r1[0] + r1[1] + r1[2] + r1[3]));
    } else {
        for (int i = tid; i < 4 * E; i += 256) {
            const float* src;
            int j;
            if (i < E)            { src = wqs; j = i; }
            else if (i < 2 * E)   { src = wks; j = i - E; }
            else if (i < 3 * E)   { src = wvs; j = i - 2 * E; }
            else                  { src = wos; j = i - 3 * E; }
            spws[i] = sp_f(src[j]);
        }
    }
}

// --------------------------------- linear (BK=32 bf16 MFMA, 128x64 tile) ---
// NBUF=2 double-buffer (round-9 proven). 48KB LDS, 3 blocks/CU. XCD-chunked
// m-fastest ordering for W-panel / A-slice L2 residency.
template<int MODE, int NBUF>
__global__ __launch_bounds__(256, 3) void linear_fused(
    const u16* __restrict__ Am, const u16* __restrict__ As,
    const u16* __restrict__ Wt, const u16* __restrict__ W2t,
    const float* __restrict__ spws, const float* __restrict__ rmu2, const float* __restrict__ rsg,
    float* __restrict__ mu_out, float* __restrict__ sg_out, u16* __restrict__ QKVB)
{
    __shared__ __align__(16) u16 L[NBUF * 12288];

    const int wgid = blockIdx.x;
    const int xcd = wgid & 7, local = wgid >> 3;
    const int m_blk = xcd * 4 + (local & 3);        // m fastest within chunk
    const int n_blk = local >> 2;
    const int m0 = m_blk * 128, col0 = n_blk * 64;
    const int tid = threadIdx.x, wv = tid >> 6, lane = tid & 63;
    const int g = lane >> 4, q15 = lane & 15;

    const u16* sp_[6];
    {
        const int rA = tid >> 2, cA = tid & 3;
        const int rB = 64 + rA;
        const int csA = (cA ^ ((rA >> 1) & 3)) << 3;
        const int csB = (cA ^ ((rB >> 1) & 3)) << 3;
        sp_[0] = Am  + (size_t)(m0 + rA) * E + csA;
        sp_[1] = Am  + (size_t)(m0 + rB) * E + csB;
        sp_[2] = As  + (size_t)(m0 + rA) * E + csA;
        sp_[3] = As  + (size_t)(m0 + rB) * E + csB;
        sp_[4] = Wt  + (size_t)(col0 + rA) * E + csA;
        sp_[5] = W2t + (size_t)(col0 + rA) * E + csA;
    }

    f32x4 acc1[2][4], acc2[2][4];
#pragma unroll
    for (int mt = 0; mt < 2; ++mt)
#pragma unroll
        for (int nt = 0; nt < 4; ++nt) {
            acc1[mt][nt] = (f32x4){0.f, 0.f, 0.f, 0.f};
            acc2[mt][nt] = (f32x4){0.f, 0.f, 0.f, 0.f};
        }

#pragma unroll
    for (int j = 0; j < 6; ++j)
        GLL16(sp_[j], &L[j * 2048 + tid * 8]);

    for (int t = 0; t < 24; ++t) {
        SBAR();
        const int tn = (t < 23) ? t + 1 : 23;
        const int nb = ((t & 1) ^ 1) * 12288;
#pragma unroll
        for (int j = 0; j < 6; ++j)
            GLL16(sp_[j] + tn * 32, &L[nb + j * 2048 + tid * 8]);
        VMCNT(6);
        SBAR();
        const int cb = (t & 1) * 12288;
        __builtin_amdgcn_s_setprio(1);   // cover LDS fragment reads + MFMA
        bf16x8 am[2], asg[2];
#pragma unroll
        for (int mt = 0; mt < 2; ++mt) {
            int r = wv * 32 + mt * 16 + q15;
            int c = (g ^ ((r >> 1) & 3)) << 3;
            am[mt]  = *(const bf16x8*)&L[cb + r * 32 + c];
            asg[mt] = *(const bf16x8*)&L[cb + 4096 + r * 32 + c];
        }
#pragma unroll
        for (int nt = 0; nt < 4; ++nt) {
            int rb = nt * 16 + q15;
            int c = (g ^ ((rb >> 1) & 3)) << 3;
            bf16x8 bw = *(const bf16x8*)&L[cb + 8192 + rb * 32 + c];
            bf16x8 b2 = *(const bf16x8*)&L[cb + 10240 + rb * 32 + c];
            acc1[0][nt] = __builtin_amdgcn_mfma_f32_16x16x32_bf16(am[0], bw, acc1[0][nt], 0, 0, 0);
            acc1[1][nt] = __builtin_amdgcn_mfma_f32_16x16x32_bf16(am[1], bw, acc1[1][nt], 0, 0, 0);
            acc2[0][nt] = __builtin_amdgcn_mfma_f32_16x16x32_bf16(asg[0], b2, acc2[0][nt], 0, 0, 0);
            acc2[1][nt] = __builtin_amdgcn_mfma_f32_16x16x32_bf16(asg[1], b2, acc2[1][nt], 0, 0, 0);
        }
        __builtin_amdgcn_s_setprio(0);
    }
    __syncthreads();

    const float inv2 = 1.f / (768.f * 768.f), invd = 1.f / 768.f;
    float rr[2][4];
#pragma unroll
    for (int mt = 0; mt < 2; ++mt)
#pragma unroll
        for (int r = 0; r < 4; ++r) {
            int row = m0 + wv * 32 + mt * 16 + g * 4 + r;
            rr[mt][r] = rmu2[row] * inv2 + rsg[row] * invd;
        }

    if (MODE == 0) {
#pragma unroll
        for (int mt = 0; mt < 2; ++mt)
#pragma unroll
            for (int nt = 0; nt < 4; ++nt)
#pragma unroll
                for (int r = 0; r < 4; ++r) {
                    int row = m0 + wv * 32 + mt * 16 + g * 4 + r;
                    int col = col0 + nt * 16 + q15;
                    float mu = acc1[mt][nt][r];
                    float sg = sp_f(sp_f(acc2[mt][nt][r] + rr[mt][r] * spws[col]));
                    mu_out[(size_t)row * E + col] = mu;
                    sg_out[(size_t)row * E + col] = sg;
                }
    } else {
        const int proj = n_blk / 12, h = n_blk % 12;
        float sgv[2][4][4];
#pragma unroll
        for (int mt = 0; mt < 2; ++mt)
#pragma unroll
            for (int nt = 0; nt < 4; ++nt)
#pragma unroll
                for (int r = 0; r < 4; ++r) {
                    int col = col0 + nt * 16 + q15;
                    sgv[mt][nt][r] = sp_f(acc2[mt][nt][r] + rr[mt][r] * spws[col]);
                }
        const int bb = m0 >> 10;
        if (proj < 2) {
            // coalesced [bh][s][d] store via LDS transpose (pad 72):
            // each thread owns a contiguous 32-u16 run (4 x uint4).
            const int s0 = (m0 & 1023);
            const int sl = tid >> 1, hh = tid & 1;
            size_t gbase = ((size_t)(bb * 12 + h) << 16) + ((size_t)(s0 + sl) << 6) + hh * 32;
#pragma unroll
            for (int a = 0; a < 3; ++a) {
                __syncthreads();
#pragma unroll
                for (int mt = 0; mt < 2; ++mt)
#pragma unroll
                    for (int nt = 0; nt < 4; ++nt)
#pragma unroll
                        for (int r = 0; r < 4; ++r) {
                            float mu = acc1[mt][nt][r], sg = sgv[mt][nt][r];
                            float v = (a == 0) ? mu : (a == 1) ? sg :
                                      (proj == 0 ? (mu * mu + sg) * QSC : mu * mu * QSC);
                            L[(wv * 32 + mt * 16 + g * 4 + r) * 72 + nt * 16 + q15] = f2bf(v);
                        }
                __syncthreads();
                u16* dst = QKVB + (size_t)(proj * 3 + a) * BFN;
#pragma unroll
                for (int j = 0; j < 4; ++j)
                    *(uint4*)(dst + gbase + j * 8) = *(const uint4*)&L[sl * 72 + hh * 32 + j * 8];
            }
        } else {
            // V: [bh][d][s], s permuted in 32-blocks (slot g*8+mt*4+r)
            const int s0 = m0 & 1023;
#pragma unroll
            for (int a = 0; a < 3; ++a) {
                __syncthreads();
#pragma unroll
                for (int mt = 0; mt < 2; ++mt)
#pragma unroll
                    for (int nt = 0; nt < 4; ++nt)
#pragma unroll
                        for (int r = 0; r < 4; ++r) {
                            float mu = acc1[mt][nt][r], sg = sgv[mt][nt][r];
                            float v = (a == 0) ? mu : (a == 1) ? sg * 0.0009765625f : mu * mu + sg;
                            L[(nt * 16 + q15) * 136 + wv * 32 + g * 8 + mt * 4 + r] = f2bf(v);
                        }
                __syncthreads();
                const int d = tid >> 2, sc = (tid & 3) * 32;
                u16* dst = QKVB + (size_t)(6 + a) * BFN;
                size_t ga = ((size_t)((bb * 12 + h) * 64 + d) << 10) + s0 + sc;
                *(uint4*)(dst + ga)      = *(const uint4*)&L[d * 136 + sc];
                *(uint4*)(dst + ga + 8)  = *(const uint4*)&L[d * 136 + sc + 8];
                *(uint4*)(dst + ga + 16) = *(const uint4*)&L[d * 136 + sc + 16];
                *(uint4*)(dst + ga + 24) = *(const uint4*)&L[d * 136 + sc + 24];
            }
        }
    }
}

// ------------------------------------------------------------- attention ---
// v9: pass 1 = 128-k tiles (8 barrier rounds, 16KB x2 bufs); pass 2 = the
// proven v8 K+V double-buffered loop; epilogue fuses row stats (Σmu², Σsg)
// via 16-lane shfl reduce + one atomicAdd per row per head.
#define KB0 0
#define KB1 6144
#define VB0 12288
#define VB1 18432
__global__ __launch_bounds__(256, 3) void vdp_attn9(
    const u16* __restrict__ Kmu, const u16* __restrict__ Ksg, const u16* __restrict__ Asq,
    const u16* __restrict__ Qmu, const u16* __restrict__ Q1v, const u16* __restrict__ Q2v,
    const u16* __restrict__ Vmu, const u16* __restrict__ Vsg, const u16* __restrict__ Vw2,
    u16* __restrict__ om, u16* __restrict__ osg,
    float* __restrict__ armu2, float* __restrict__ arsg)
{
    __shared__ __align__(16) u16 L[24576];   // 48KB

    const int wgid = blockIdx.x;                  // 768 = 48bh x 16qt
    const int seq = (wgid & 7) * 96 + (wgid >> 3);
    const int bh = seq >> 4, qt = seq & 15;
    const int tid = threadIdx.x, wv = tid >> 6, lane = tid & 63;
    const int g = lane >> 4, q15 = lane & 15;
    const size_t hb = (size_t)bh << 16;

    const size_t qoff = hb + (size_t)((qt * 64 + wv * 16 + q15) << 6) + g * 8;
    bf16x8 bq0 = *(const bf16x8*)(Qmu + qoff), bq1 = *(const bf16x8*)(Qmu + qoff + 32);
    bf16x8 b10 = *(const bf16x8*)(Q1v + qoff), b11 = *(const bf16x8*)(Q1v + qoff + 32);
    bf16x8 b20 = *(const bf16x8*)(Q2v + qoff), b21 = *(const bf16x8*)(Q2v + qoff + 32);

    const int sr = tid >> 3, sc8 = tid & 7;
    const size_t koffA = hb + (size_t)sr * 64 + ((sc8 ^ (sr & 7)) << 3);
    const int vr = tid >> 2, vc = tid & 3;
    const size_t voff = hb + (size_t)vr * 1024 + ((vc ^ ((vr >> 1) & 3)) << 3);

    // ---- pass 1: softmax stats over 128-k tiles (8 rounds, bufs @0 / @8192)
    float m2 = -3.0e38f;
    float lacc[4] = {0.f, 0.f, 0.f, 0.f};
#pragma unroll
    for (int s = 0; s < 4; ++s)
        GLL16(Kmu + koffA + s * 2048, &L[s * 2048 + tid * 8]);
    __syncthreads();
    for (int t = 0; t < 8; ++t) {
        SBAR();
        const int tn = (t < 7) ? t + 1 : 7;
        const int nb = (t & 1) ? 0 : 8192;
#pragma unroll
        for (int s = 0; s < 4; ++s)
            GLL16(Kmu + koffA + (size_t)tn * 8192 + s * 2048, &L[nb + s * 2048 + tid * 8]);
        VMCNT(4);
        SBAR();
        const int kb = (t & 1) ? 8192 : 0;
        f32x4 sc[8];
#pragma unroll
        for (int kt = 0; kt < 8; ++kt) sc[kt] = (f32x4){0.f, 0.f, 0.f, 0.f};
        __builtin_amdgcn_s_setprio(1);
#pragma unroll
        for (int kt = 0; kt < 8; ++kt) {
            int row = kt * 16 + q15, ra = kb + (row << 6);
            bf16x8 k0 = *(const bf16x8*)&L[ra + ((g ^ (row & 7)) << 3)];
            bf16x8 k1 = *(const bf16x8*)&L[ra + (((g + 4) ^ (row & 7)) << 3)];
            sc[kt] = __builtin_amdgcn_mfma_f32_16x16x32_bf16(k0, bq0, sc[kt], 0, 0, 0);
            sc[kt] = __builtin_amdgcn_mfma_f32_16x16x32_bf16(k1, bq1, sc[kt], 0, 0, 0);
        }
        __builtin_amdgcn_s_setprio(0);
        float tmx = -3.0e38f;
#pragma unroll
        for (int kt = 0; kt < 8; ++kt)
#pragma unroll
            for (int r = 0; r < 4; ++r) tmx = fmaxf(tmx, sc[kt][r]);
        tmx *= C2E;
        if (tmx > m2 + 8.f) {
            float f = ex2(m2 - tmx);
            lacc[0] *= f; lacc[1] *= f; lacc[2] *= f; lacc[3] *= f;
            m2 = tmx;
        }
#pragma unroll
        for (int kt = 0; kt < 8; ++kt)
#pragma unroll
            for (int r = 0; r < 4; ++r)
                lacc[kt & 3] += ex2(fmaf(sc[kt][r], C2E, -m2));
    }
    __syncthreads();
    float l = (lacc[0] + lacc[1]) + (lacc[2] + lacc[3]);
#pragma unroll
    for (int off = 16; off <= 32; off <<= 1) {
        float mo = __shfl_xor(m2, off), lo = __shfl_xor(l, off);
        float nm = fmaxf(m2, mo);
        l = l * ex2(m2 - nm) + lo * ex2(mo - nm);
        m2 = nm;
    }
    const float M = m2 + lg2(l);

    // ---- pass 2: K and V both double-buffered (v8 proven)
    f32x4 accm[4], accd[4], acce[4];
#pragma unroll
    for (int nt = 0; nt < 4; ++nt) {
        accm[nt] = (f32x4){0.f, 0.f, 0.f, 0.f};
        accd[nt] = (f32x4){0.f, 0.f, 0.f, 0.f};
        acce[nt] = (f32x4){0.f, 0.f, 0.f, 0.f};
    }

    GLL16(Kmu + koffA, &L[KB0 + 0    + wv * 512]);
    GLL16(Ksg + koffA, &L[KB0 + 2048 + wv * 512]);
    GLL16(Asq + koffA, &L[KB0 + 4096 + wv * 512]);
    GLL16(Vmu + voff, &L[VB0 + 0    + wv * 512]);
    GLL16(Vsg + voff, &L[VB0 + 2048 + wv * 512]);
    GLL16(Vw2 + voff, &L[VB0 + 4096 + wv * 512]);
    __syncthreads();

    for (int t = 0; t < 32; ++t) {
        SBAR();                                   // buf[cur^1] free to overwrite
        const int tn = (t < 31) ? t + 1 : 31;
        const size_t ka = (size_t)tn << 11;
        const size_t va = (size_t)tn << 5;
        const int nbK = (t & 1) ? KB0 : KB1;
        const int nbV = (t & 1) ? VB0 : VB1;
        GLL16(Kmu + koffA + ka, &L[nbK + 0    + wv * 512]);
        GLL16(Ksg + koffA + ka, &L[nbK + 2048 + wv * 512]);
        GLL16(Asq + koffA + ka, &L[nbK + 4096 + wv * 512]);
        GLL16(Vmu + voff + va,  &L[nbV + 0    + wv * 512]);
        GLL16(Vsg + voff + va,  &L[nbV + 2048 + wv * 512]);
        GLL16(Vw2 + voff + va,  &L[nbV + 4096 + wv * 512]);
        VMCNT(6);                                 // K(t),V(t) landed (mine)
        SBAR();                                   // ... for everyone

        const int kb = (t & 1) ? KB1 : KB0;
        const int vb = (t & 1) ? VB1 : VB0;
        f32x4 sc[2], sgc[2];
#pragma unroll
        for (int kt = 0; kt < 2; ++kt) { sc[kt] = (f32x4){0.f,0.f,0.f,0.f}; sgc[kt] = (f32x4){0.f,0.f,0.f,0.f}; }
        __builtin_amdgcn_s_setprio(1);
#pragma unroll
        for (int kt = 0; kt < 2; ++kt) {
            int row = kt * 16 + q15, ra = kb + (row << 6);
            int ca = ((g ^ (row & 7)) << 3), cb = (((g + 4) ^ (row & 7)) << 3);
            sc[kt]  = __builtin_amdgcn_mfma_f32_16x16x32_bf16(*(const bf16x8*)&L[ra + ca],        bq0, sc[kt],  0, 0, 0);
            sc[kt]  = __builtin_amdgcn_mfma_f32_16x16x32_bf16(*(const bf16x8*)&L[ra + cb],        bq1, sc[kt],  0, 0, 0);
            sgc[kt] = __builtin_amdgcn_mfma_f32_16x16x32_bf16(*(const bf16x8*)&L[2048 + ra + ca], b10, sgc[kt], 0, 0, 0);
            sgc[kt] = __builtin_amdgcn_mfma_f32_16x16x32_bf16(*(const bf16x8*)&L[2048 + ra + cb], b11, sgc[kt], 0, 0, 0);
            sgc[kt] = __builtin_amdgcn_mfma_f32_16x16x32_bf16(*(const bf16x8*)&L[4096 + ra + ca], b20, sgc[kt], 0, 0, 0);
            sgc[kt] = __builtin_amdgcn_mfma_f32_16x16x32_bf16(*(const bf16x8*)&L[4096 + ra + cb], b21, sgc[kt], 0, 0, 0);
        }
        __builtin_amdgcn_s_setprio(0);

        float p[8], p2v[8], swv[8];
#pragma unroll
        for (int kt = 0; kt < 2; ++kt)
#pragma unroll
            for (int r = 0; r < 4; ++r) {
                int j = kt * 4 + r;
                float pv = ex2(fmaf(sc[kt][r], C2E, -M));
                float pp = pv * pv;
                float gq = pv - pp;
                p[j] = pv; p2v[j] = pp; swv[j] = gq * gq * sgc[kt][r];
            }
        u32x4 ua  = {cvtpk(p[0], p[1]),     cvtpk(p[2], p[3]),     cvtpk(p[4], p[5]),     cvtpk(p[6], p[7])};
        u32x4 ubv = {cvtpk(p2v[0], p2v[1]), cvtpk(p2v[2], p2v[3]), cvtpk(p2v[4], p2v[5]), cvtpk(p2v[6], p2v[7])};
        u32x4 ucv = {cvtpk(swv[0], swv[1]), cvtpk(swv[2], swv[3]), cvtpk(swv[4], swv[5]), cvtpk(swv[6], swv[7])};
        bf16x8 pa  = *(const bf16x8*)&ua;
        bf16x8 p2a = *(const bf16x8*)&ubv;
        bf16x8 swa = *(const bf16x8*)&ucv;

        __builtin_amdgcn_s_setprio(1);
#pragma unroll
        for (int nt = 0; nt < 4; ++nt) {
            int row = nt * 16 + q15;
            int vi = vb + (row << 5) + ((g ^ ((q15 >> 1) & 3)) << 3);
            accm[nt] = __builtin_amdgcn_mfma_f32_16x16x32_bf16(pa,  *(const bf16x8*)&L[vi],        accm[nt], 0, 0, 0);
            accd[nt] = __builtin_amdgcn_mfma_f32_16x16x32_bf16(p2a, *(const bf16x8*)&L[vi + 2048], accd[nt], 0, 0, 0);
            acce[nt] = __builtin_amdgcn_mfma_f32_16x16x32_bf16(swa, *(const bf16x8*)&L[vi + 4096], acce[nt], 0, 0, 0);
        }
        __builtin_amdgcn_s_setprio(0);
    }

    // ---- epilogue: store bf16 + fused row stats (per-row shfl reduce + atomic)
    const int b_ = bh / 12, h_ = bh % 12;
#pragma unroll
    for (int r = 0; r < 4; ++r) {
        int srow = qt * 64 + wv * 16 + g * 4 + r;
        int n = b_ * 1024 + srow;
        float s1 = 0.f, s2 = 0.f;
#pragma unroll
        for (int nt = 0; nt < 4; ++nt) {
            int d = nt * 16 + q15;
            float mu = accm[nt][r];
            float sg = sp_f(accd[nt][r] + acce[nt][r]);
            size_t o = (size_t)n * E + h_ * 64 + d;
            om[o]  = f2bf(mu);
            osg[o] = f2bf(sg);
            s1 += mu * mu;
            s2 += sg;
        }
#pragma unroll
        for (int off = 1; off < 16; off <<= 1) {
            s1 += __shfl_xor(s1, off);
            s2 += __shfl_xor(s2, off);
        }
        if (q15 == 0) {
            atomicAdd(&armu2[n], s1);
            atomicAdd(&arsg[n], s2);
        }
    }
}

// --------------------------------------------------------------- launch ----
extern "C" void kernel_launch(void* const* d_in, const int* in_sizes, int n_in,
                              void* d_out, int out_size, void* d_ws, size_t ws_size,
                              hipStream_t stream)
{
    const float* mu_in = (const float*)d_in[0];
    const float* sg_in = (const float*)d_in[1];
    const float* wq  = (const float*)d_in[2];
    const float* wqs = (const float*)d_in[3];
    const float* wk  = (const float*)d_in[4];
    const float* wks = (const float*)d_in[5];
    const float* wvp = (const float*)d_in[6];
    const float* wvs = (const float*)d_in[7];
    const float* wo  = (const float*)d_in[8];
    const float* wos = (const float*)d_in[9];

    float* out_mu = (float*)d_out;
    float* out_sg = out_mu + (size_t)NTOK * E;
    float* kl_out = out_mu + 2 * (size_t)NTOK * E;

    float* ws = (float*)d_ws;
    size_t off = 0;
    auto allocf = [&](size_t n) { float* p = ws + off; off += n; return p; };
    float* rmu2  = allocf(NTOK);
    float* rsgs  = allocf(NTOK);
    float* armu2 = allocf(NTOK);
    float* arsg  = allocf(NTOK);
    float* spws  = allocf(4 * E);

    u16* ub = (u16*)(ws + off);
    size_t uoff = 0;
    auto allocu = [&](size_t n) { u16* p = ub + uoff; uoff += n; return p; };
    u16* Xmu    = allocu(BFN);
    u16* Xsg    = allocu(BFN);
    u16* WtAll  = allocu(4 * WFN);
    u16* W2tAll = allocu(4 * WFN);
    u16* QKVB   = allocu(9 * BFN);
    u16* amu_b  = allocu(BFN);
    u16* asg_b  = allocu(BFN);
    (void)ws_size; (void)in_sizes; (void)n_in; (void)out_size;

    hipMemsetAsync(kl_out, 0, 4, stream);
    hipMemsetAsync(armu2, 0, 2 * NTOK * sizeof(float), stream);  // armu2+arsg contiguous
    prep_all<<<4865, 256, 0, stream>>>(mu_in, sg_in, wq, wk, wvp, wo,
                                       wqs, wks, wvs, wos,
                                       Xmu, Xsg, rmu2, rsgs, WtAll, W2tAll,
                                       spws, kl_out);

    linear_fused<1, 2><<<1152, 256, 0, stream>>>(Xmu, Xsg, WtAll, W2tAll, spws, rmu2, rsgs,
                                                 nullptr, nullptr, QKVB);

    vdp_attn9<<<768, 256, 0, stream>>>(QKVB + 3 * BFN, QKVB + 4 * BFN, QKVB + 1 * BFN,
                                       QKVB + 0 * BFN, QKVB + 2 * BFN, QKVB + 5 * BFN,
                                       QKVB + 6 * BFN, QKVB + 7 * BFN, QKVB + 8 * BFN,
                                       amu_b, asg_b, armu2, arsg);

    linear_fused<0, 2><<<384, 256, 0, stream>>>(amu_b, asg_b, WtAll + 3 * WFN, W2tAll + 3 * WFN,
                                                spws + 3 * E, armu2, arsg,
                                                out_mu, out_sg, nullptr);
}